// Round 7
// baseline (266.312 us; speedup 1.0000x reference)
//
#include <hip/hip_runtime.h>

// ---------------------------------------------------------------------------
// context = softmax((q@Wq+bq)(k@Wk+bk)^T / 32) @ (v@Wv+bv)
// S=4096, H=D=1024. fp32 in/out, bf16 MFMA internally.
//
// GEMM core (gemm128): 128x256 tile, 512 threads (8 waves, 2m x 4n of 64x64),
// BK=32 chunks through a 2-slot LDS ring (2 x 24KB = 48KB), 2 blocks/CU.
// Core uses 32x32x16 MFMA (same FLOP as 16x16x32, half the instructions,
// +20% pipe ceiling per m119). Per chunk per wave:
// 8x ds_read_b128 (4 A-frags, 4 B-frags) + 8x mfma_f32_32x32x16_bf16.
// Staging, LDS layout, XOR swizzle, barrier rhythm identical to round 5
// (which passed with SQ_LDS_BANK_CONFLICT=0).
// (Round 6 submission was identical; bench infra failed twice -> resubmit.)
//
// LDS bank swizzle: logical 16B col k8 of row r lives at physical col
// k8 ^ (((r mod 16)>>1)&3). Staging keeps linear global_load_lds dest and
// pre-swizzles the per-lane GLOBAL k-offset (l&3)^((l>>3)&3).
// 32x32 read map: row_local = i*32 + (lane&31), logical col = 2h + (lane>>5)
// -> physical col = (2h + (lane>>5)) ^ (((lane&31)>>1)&3)  (per-lane const;
// bits 1-2 of lane&31 equal bits 1-2 of (lane&31) mod 16, so key matches
// the write side for all 32 rows).
//
// ws layout (MB):
//   [ 0, 6)  Wt  bf16 [3][1024][1024]      (W^T, per projection)
//   [ 6,30)  xb  bf16 [3][4096][1024]      (q,k,v cast)
//   [30,54)  pr  bf16 [3][4096][1024]      (Q,K,Vn projections; z-contiguous)
//   [46,78)  S   bf16 [4096][4096]         (overwrites dead Vn after transpose)
//   [78,86)  Vt  bf16 [1024][4096]
//   [ 0,16)  p1, [16,32) p2  fp32 partials (dead Wt/xb region at PV time)
//   [86,102) p3 fp32 partial               (only if ws_size >= 102MB -> SK=4)
// ---------------------------------------------------------------------------

typedef short short4v __attribute__((ext_vector_type(4)));
typedef short short8  __attribute__((ext_vector_type(8)));
typedef float f32x4   __attribute__((ext_vector_type(4)));
typedef float f32x16  __attribute__((ext_vector_type(16)));

#define MFMA32 __builtin_amdgcn_mfma_f32_32x32x16_bf16

__device__ __forceinline__ short f2bf(float f) {
    union { float f; unsigned u; } x; x.f = f;
    unsigned r = (x.u + 0x7FFFu + ((x.u >> 16) & 1u)) >> 16;  // RNE
    return (short)r;
}
__device__ __forceinline__ float bf2f(short s) {
    union { unsigned u; float f; } x;
    x.u = ((unsigned)(unsigned short)s) << 16; return x.f;
}
__device__ __forceinline__ void store_out(short* p, float v) { *p = f2bf(v); }
__device__ __forceinline__ void store_out(float* p, float v) { *p = v; }

// async global->LDS, 16B/lane. LDS dest = wave-uniform base + lane*16.
__device__ __forceinline__ void gl2lds(const short* g, short* l) {
    __builtin_amdgcn_global_load_lds(
        (const __attribute__((address_space(1))) void*)g,
        (__attribute__((address_space(3))) void*)l, 16, 0, 0);
}

// --- W[k][n] fp32 -> Wt[z][n][k] bf16 ------------------------------------
__global__ __launch_bounds__(256) void prep_w(
    const float* __restrict__ W0, const float* __restrict__ W1,
    const float* __restrict__ W2, short* __restrict__ Wt)
{
    __shared__ float tile[64][65];
    const float* W = blockIdx.z == 0 ? W0 : (blockIdx.z == 1 ? W1 : W2);
    short* T = Wt + (size_t)blockIdx.z * 1048576;
    const int c0 = blockIdx.x * 64;
    const int r0 = blockIdx.y * 64;
    const int tx = threadIdx.x & 63;
    const int ty = threadIdx.x >> 6;
    #pragma unroll
    for (int p = 0; p < 16; ++p) {
        int r = ty + p * 4;
        tile[r][tx] = W[(size_t)(r0 + r) * 1024 + c0 + tx];
    }
    __syncthreads();
    #pragma unroll
    for (int p = 0; p < 16; ++p) {
        int r = ty + p * 4;
        T[(size_t)(c0 + r) * 1024 + r0 + tx] = f2bf(tile[tx][r]);
    }
}

// --- q,k,v fp32 -> xb bf16 -----------------------------------------------
__global__ __launch_bounds__(256) void cast_qkv(
    const float* __restrict__ q, const float* __restrict__ k,
    const float* __restrict__ v, short* __restrict__ xb)
{
    const float* src = blockIdx.z == 0 ? q : (blockIdx.z == 1 ? k : v);
    short* dst = xb + (size_t)blockIdx.z * 4194304;
    for (int i = blockIdx.x * 256 + threadIdx.x; i < 1048576; i += 256 * 1024) {
        float4 f = ((const float4*)src)[i];
        short4v o;
        o[0] = f2bf(f.x); o[1] = f2bf(f.y); o[2] = f2bf(f.z); o[3] = f2bf(f.w);
        ((short4v*)dst)[i] = o;
    }
}

// --- Vn bf16 [4096][1024] -> Vt bf16 [1024][4096] -------------------------
__global__ __launch_bounds__(256) void transpose_v(
    const short* __restrict__ src, short* __restrict__ dst)
{
    __shared__ short t[64][65];
    const int c0 = blockIdx.x * 64;   // src col block (dst row block)
    const int r0 = blockIdx.y * 64;   // src row block
    const int tx = threadIdx.x & 63;
    const int ty = threadIdx.x >> 6;
    #pragma unroll
    for (int p = 0; p < 16; ++p) {
        const int r = p * 4 + ty;
        t[r][tx] = src[(size_t)(r0 + r) * 1024 + c0 + tx];
    }
    __syncthreads();
    #pragma unroll
    for (int p = 0; p < 16; ++p) {
        const int r = p * 4 + ty;
        dst[(size_t)(c0 + r) * 4096 + r0 + tx] = t[tx][r];
    }
}

// --- bf16 GEMM core: C = scale*(A @ Bt^T) [+ bias] ------------------------
// 128x256 tile, 8 waves (2m x 4n, 64x64 each), 2-slot LDS ring, BK=32,
// 32x32x16 MFMA (2x2 frags per wave).
// MODE 0: plain. MODE 1: z selects {A,Bt,C,bias} (batched projections).
// MODE 2: z is split-K index; C-dst = {C, P1, P2, P3}[z].
template <typename TOut, int MODE>
__global__ __launch_bounds__(512, 4) void gemm128(
    const short* __restrict__ A, const short* __restrict__ Bt,
    const float* __restrict__ b0, const float* __restrict__ b1,
    const float* __restrict__ b2,
    TOut* __restrict__ C, float* __restrict__ P1, float* __restrict__ P2,
    float* __restrict__ P3,
    int M, int N, int lda, int ldb, float scale,
    int nc, int nc_last, int kstep)
{
    // 2 slots x { A [128 rows][64B] = 8KB , B [256 rows][64B] = 16KB } = 48KB
    __shared__ short Lds[24576];

    const int t    = threadIdx.x;
    const int lane = t & 63;
    const int wv   = t >> 6;

    // ---- band-swizzled grid (XCD L2 locality): XCD x keeps m==x (mod 8). -
    const int nb  = gridDim.x;                    // n-tiles
    const int bid = blockIdx.y * nb + blockIdx.x;
    const int band   = bid / (8 * nb);
    const int within = bid - band * 8 * nb;
    const int m0 = (band * 8 + (within & 7)) * 128;
    const int n0 = (within >> 3) * 256;

    const float* bias = nullptr;
    int kbeg = 0;
    TOut* Cw = C;
    if constexpr (MODE == 1) {
        const int z = blockIdx.z;
        A  += (size_t)z * M * lda;
        Bt += (size_t)z * N * ldb;
        Cw  = C + (size_t)z * M * N;
        bias = z == 0 ? b0 : (z == 1 ? b1 : b2);
    }
    if constexpr (MODE == 2) {
        const int z = blockIdx.z;
        kbeg = z * kstep;
        if (z == (int)gridDim.z - 1) nc = nc_last;
        Cw = (TOut*)(z == 0 ? (float*)C : (z == 1 ? P1 : (z == 2 ? P2 : P3)));
    }
    (void)b0; (void)b1; (void)b2; (void)P1; (void)P2; (void)P3;
    (void)nc_last; (void)kstep;

    // ---- staging map (identical to round 5): per chunk each wave issues
    // 3 gl2lds (1KB each): A rows [wv*16,+16); B rows [wv*16,+16) and +128.
    // lane l -> row += l>>2, global 16B-col pre-swizzled (l&3)^((l>>3)&3).
    const int srow = lane >> 2;
    const int skof = ((lane & 3) ^ ((lane >> 3) & 3)) * 8;
    const short* pA  = A  + (size_t)(m0 + wv * 16 + srow) * lda + kbeg + skof;
    const short* pB0 = Bt + (size_t)(n0 + wv * 16 + srow) * ldb + kbeg + skof;
    const short* pB1 = pB0 + (size_t)128 * ldb;
    short* sA  = Lds + wv * 512;            // wave-uniform LDS bases (shorts)
    short* sB0 = Lds + 4096 + wv * 512;
    short* sB1 = Lds + 8192 + wv * 512;

    // ---- fragment read map (32x32x16: row = lane&31, k-half = lane>>5) ---
    // physical 16B col = (2h + hb) ^ ((rl>>1)&3); per-lane constants:
    const int wm = wv >> 2, wn = wv & 3;    // 2m x 4n wave grid
    const int rl = lane & 31, hb = lane >> 5;
    const int key = (rl >> 1) & 3;
    const int cp0 = ((hb) ^ key) * 8;       // h=0 col offset (shorts)
    const int cp1 = ((2 | hb) ^ key) * 8;   // h=1 col offset (shorts)
    const short* rdA = Lds + (wm * 64 + rl) * 32;
    const short* rdB = Lds + 4096 + (wn * 64 + rl) * 32;

    f32x16 acc[2][2];
    #pragma unroll
    for (int i = 0; i < 2; ++i)
        #pragma unroll
        for (int j = 0; j < 2; ++j)
            #pragma unroll
            for (int q = 0; q < 16; ++q) acc[i][j][q] = 0.f;

#define STAGE(c) {                                                        \
    const int s_ = (c) & 1;                                               \
    const size_t ko_ = (size_t)(c) * 32;                                  \
    gl2lds(pA  + ko_, sA  + s_ * 12288);                                  \
    gl2lds(pB0 + ko_, sB0 + s_ * 12288);                                  \
    gl2lds(pB1 + ko_, sB1 + s_ * 12288); }

#define COMPUTE(c) {                                                      \
    const short* aB = rdA + ((c) & 1) * 12288;                            \
    const short* bB = rdB + ((c) & 1) * 12288;                            \
    short8 a00 = *(const short8*)(aB + cp0);                              \
    short8 a01 = *(const short8*)(aB + cp1);                              \
    short8 a10 = *(const short8*)(aB + 1024 + cp0);                       \
    short8 a11 = *(const short8*)(aB + 1024 + cp1);                       \
    short8 b00 = *(const short8*)(bB + cp0);                              \
    short8 b01 = *(const short8*)(bB + cp1);                              \
    short8 b10 = *(const short8*)(bB + 1024 + cp0);                       \
    short8 b11 = *(const short8*)(bB + 1024 + cp1);                       \
    __builtin_amdgcn_s_setprio(1);                                        \
    acc[0][0] = MFMA32(a00, b00, acc[0][0], 0, 0, 0);                     \
    acc[0][0] = MFMA32(a01, b01, acc[0][0], 0, 0, 0);                     \
    acc[0][1] = MFMA32(a00, b10, acc[0][1], 0, 0, 0);                     \
    acc[0][1] = MFMA32(a01, b11, acc[0][1], 0, 0, 0);                     \
    acc[1][0] = MFMA32(a10, b00, acc[1][0], 0, 0, 0);                     \
    acc[1][0] = MFMA32(a11, b01, acc[1][0], 0, 0, 0);                     \
    acc[1][1] = MFMA32(a10, b10, acc[1][1], 0, 0, 0);                     \
    acc[1][1] = MFMA32(a11, b11, acc[1][1], 0, 0, 0);                     \
    __builtin_amdgcn_s_setprio(0); }

    // prologue: chunk 0 in flight.
    STAGE(0);

    // main loop: stage c+1, retire c (vmcnt(3) = leave c+1's 3 in flight),
    // barrier (all waves' c resident), compute c, barrier (slot (c+1)&1's
    // old reads drained before next iter's STAGE(c+2) overwrites it).
    for (int c = 0; c < nc - 1; ++c) {
        STAGE(c + 1);
        asm volatile("s_waitcnt vmcnt(3)" ::: "memory");
        __builtin_amdgcn_s_barrier();
        COMPUTE(c);
        __builtin_amdgcn_s_barrier();
    }
    // tail: no stage; drain and compute last chunk.
    asm volatile("s_waitcnt vmcnt(0)" ::: "memory");
    __builtin_amdgcn_s_barrier();
    COMPUTE(nc - 1);
#undef COMPUTE
#undef STAGE

    // ---- epilogue: 32x32 C/D layout col=lane&31,
    //      row = (reg&3) + 8*(reg>>2) + 4*(lane>>5) --------------------
    #pragma unroll
    for (int i = 0; i < 2; ++i) {
        #pragma unroll
        for (int j = 0; j < 2; ++j) {
            const int ccol = n0 + wn * 64 + j * 32 + rl;
            float bb = 0.f;
            if constexpr (MODE == 1) bb = bias[ccol];
            #pragma unroll
            for (int q = 0; q < 16; ++q) {
                const int crow = m0 + wm * 64 + i * 32 +
                                 (q & 3) + 8 * (q >> 2) + 4 * hb;
                float val = acc[i][j][q] * scale + bb;
                store_out(&Cw[(size_t)crow * N + ccol], val);
            }
        }
    }
}

// --- row softmax in place over bf16 S[4096][4096] -------------------------
__global__ __launch_bounds__(256) void softmax_bf16(short* __restrict__ S)
{
    const int row = blockIdx.x;
    short8* r8 = (short8*)(S + (size_t)row * 4096);
    const int t = threadIdx.x;

    float x[16];
    #pragma unroll
    for (int i = 0; i < 2; ++i) {
        short8 raw = r8[t + 256 * i];
        #pragma unroll
        for (int j = 0; j < 8; ++j) x[8 * i + j] = bf2f(raw[j]);
    }
    float m = -1e30f;
    #pragma unroll
    for (int i = 0; i < 16; ++i) m = fmaxf(m, x[i]);
    #pragma unroll
    for (int off = 32; off > 0; off >>= 1) m = fmaxf(m, __shfl_xor(m, off));

    __shared__ float redm[4], reds[4];
    const int wv = t >> 6;
    if ((t & 63) == 0) redm[wv] = m;
    __syncthreads();
    m = fmaxf(fmaxf(redm[0], redm[1]), fmaxf(redm[2], redm[3]));

    float s = 0.f;
    #pragma unroll
    for (int i = 0; i < 16; ++i) { x[i] = __expf(x[i] - m); s += x[i]; }
    #pragma unroll
    for (int off = 32; off > 0; off >>= 1) s += __shfl_xor(s, off);
    if ((t & 63) == 0) reds[wv] = s;
    __syncthreads();
    s = reds[0] + reds[1] + reds[2] + reds[3];
    const float inv = 1.f / s;

    #pragma unroll
    for (int i = 0; i < 2; ++i) {
        short8 o;
        #pragma unroll
        for (int j = 0; j < 8; ++j) o[j] = f2bf(x[8 * i + j] * inv);
        r8[t + 256 * i] = o;
    }
}

// --- out += p1 + p2 (+ p3) (split-K combine, in place) --------------------
__global__ __launch_bounds__(256) void combine(
    float* __restrict__ out, const float* __restrict__ a,
    const float* __restrict__ b, const float* __restrict__ c, int np)
{
    for (int i = blockIdx.x * 256 + threadIdx.x; i < 1048576; i += 256 * 1024) {
        float4 o = ((const float4*)out)[i];
        float4 x = ((const float4*)a)[i];
        float4 y = ((const float4*)b)[i];
        o.x += x.x + y.x; o.y += x.y + y.y;
        o.z += x.z + y.z; o.w += x.w + y.w;
        if (np == 3) {
            float4 w = ((const float4*)c)[i];
            o.x += w.x; o.y += w.y; o.z += w.z; o.w += w.w;
        }
        ((float4*)out)[i] = o;
    }
}

extern "C" void kernel_launch(void* const* d_in, const int* in_sizes, int n_in,
                              void* d_out, int out_size, void* d_ws, size_t ws_size,
                              hipStream_t stream)
{
    const float* q  = (const float*)d_in[0];
    const float* k  = (const float*)d_in[1];
    const float* v  = (const float*)d_in[2];
    const float* Wq = (const float*)d_in[3];
    const float* bq = (const float*)d_in[4];
    const float* Wk = (const float*)d_in[5];
    const float* bk = (const float*)d_in[6];
    const float* Wv = (const float*)d_in[7];
    const float* bv = (const float*)d_in[8];
    float* out = (float*)d_out;

    char* ws = (char*)d_ws;
    const size_t MB = 1ull << 20;
    short* Wt = (short*)(ws + 0);           // 3 x 1M shorts
    short* xb = (short*)(ws + 6 * MB);      // 3 x 4M shorts
    short* pr = (short*)(ws + 30 * MB);     // 3 x 4M shorts: Q, K, Vn
    short* S  = (short*)(ws + 46 * MB);     // 16M shorts (overwrites dead Vn)
    short* Vt = (short*)(ws + 78 * MB);     // 4M shorts
    float* p1 = (float*)(ws + 0);           // dead Wt/xb region by PV time
    float* p2 = (float*)(ws + 16 * MB);
    float* p3 = (float*)(ws + 86 * MB);     // extra space, if available
    const int SK = (ws_size >= 102 * MB) ? 4 : 3;

    // 1) W^T + cast, q/k/v cast
    prep_w<<<dim3(16, 16, 3), 256, 0, stream>>>(Wq, Wk, Wv, Wt);
    cast_qkv<<<dim3(1024, 1, 3), 256, 0, stream>>>(q, k, v, xb);
    // 2) projections: Q,K,Vn -> pr (z-batched); grid 4n x 32m x 3 = 384 blocks
    gemm128<short, 1><<<dim3(4, 32, 3), 512, 0, stream>>>(
        xb, Wt, bq, bk, bv, pr, nullptr, nullptr, nullptr,
        4096, 1024, 1024, 1024, 1.f, 32, 32, 0);
    // 3) Vn -> Vt (then Vn region is dead; S may overwrite it)
    transpose_v<<<dim3(16, 64), 256, 0, stream>>>(pr + 8 * 1024 * 1024, Vt);
    // 4) S = Q K^T / 32 ; grid 16n x 32m = 512 blocks (2/CU)
    gemm128<short, 0><<<dim3(16, 32), 512, 0, stream>>>(
        pr, pr + 4 * 1024 * 1024, nullptr, nullptr, nullptr, S,
        nullptr, nullptr, nullptr,
        4096, 4096, 1024, 1024, 0.03125f, 32, 32, 0);
    // 5) softmax rows in place (bf16)
    softmax_bf16<<<4096, 256, 0, stream>>>(S);
    // 6) partials = P @ V  (split-K; z=0 writes straight to out)
    if (SK == 4) {
        gemm128<float, 2><<<dim3(4, 32, 4), 512, 0, stream>>>(
            S, Vt, nullptr, nullptr, nullptr, out, p1, p2, p3,
            4096, 1024, 4096, 4096, 1.f, 32, 32, 1024);
        combine<<<1024, 256, 0, stream>>>(out, p1, p2, p3, 3);
    } else {
        gemm128<float, 2><<<dim3(4, 32, 3), 512, 0, stream>>>(
            S, Vt, nullptr, nullptr, nullptr, out, p1, p2, nullptr,
            4096, 1024, 4096, 4096, 1.f, 42, 44, 1344);
        combine<<<1024, 256, 0, stream>>>(out, p1, p2, nullptr, 2);
    }
}

// Round 8
// 263.010 us; speedup vs baseline: 1.0126x; 1.0126x over previous
//
#include <hip/hip_runtime.h>

// ---------------------------------------------------------------------------
// context = softmax((q@Wq+bq)(k@Wk+bk)^T / 32) @ (v@Wv+bv)
// S=4096, H=D=1024. fp32 in/out, bf16 MFMA internally.
//
// GEMM core (gemm128): 128x128 tile, 256 threads (4 waves, 2x2 of 64x64),
// BK=32 chunks through a 2-slot LDS ring (2 x 16KB = 32KB) -> 4 blocks/CU
// on QK (grid 1024), 3/CU on proj/PV. Round-5 mechanics (verified, 0 bank
// conflicts): 16x16x32 MFMA, XOR swizzle, counted-vmcnt rhythm:
//   STAGE(c+1) [4 gl2lds/wave] | vmcnt(4) | barrier |
//   8x ds_read_b128 + 16x MFMA (setprio) | barrier.
// Rationale: occupancy is the only lever that measured positive (r5: 1->2
// blocks/CU = -7%); r7's 32x32x16 shape regressed (4.19M bank conflicts).
// V-projection (z==2) writes Vt DIRECTLY via 2-pass LDS-transpose epilogue
// (round-0-verified pattern) -- kills transpose_v launch + Vn traffic.
//
// LDS bank swizzle: logical 16B col k8 of row r lives at physical col
// k8 ^ ((r>>1)&3). Reads use lq ^ ((lr>>1)&3) (lane-constant); staging keeps
// linear global_load_lds dest, pre-swizzles per-lane GLOBAL k-offset
// (l&3)^((l>>3)&3). Verified conflict-free (rounds 2/5).
//
// ws layout (MB):
//   [ 0, 6)  Wt  bf16 [3][1024][1024]      (W^T, per projection)
//   [ 6,30)  xb  bf16 [3][4096][1024]      (q,k,v cast)
//   [30,46)  pr  bf16 [2][4096][1024]      (Q,K projections)
//   [46,78)  S   bf16 [4096][4096]
//   [78,86)  Vt  bf16 [1024][4096]         (written by V-proj epilogue)
//   [ 0,16)  p1, [16,32) p2  fp32 partials (dead Wt/xb region at PV time)
//   [86,102) p3 fp32 partial               (only if ws_size >= 102MB -> SK=4)
// ---------------------------------------------------------------------------

typedef short short4v __attribute__((ext_vector_type(4)));
typedef short short8  __attribute__((ext_vector_type(8)));
typedef float f32x4   __attribute__((ext_vector_type(4)));

#define MFMA16 __builtin_amdgcn_mfma_f32_16x16x32_bf16

__device__ __forceinline__ short f2bf(float f) {
    union { float f; unsigned u; } x; x.f = f;
    unsigned r = (x.u + 0x7FFFu + ((x.u >> 16) & 1u)) >> 16;  // RNE
    return (short)r;
}
__device__ __forceinline__ float bf2f(short s) {
    union { unsigned u; float f; } x;
    x.u = ((unsigned)(unsigned short)s) << 16; return x.f;
}
__device__ __forceinline__ void store_out(short* p, float v) { *p = f2bf(v); }
__device__ __forceinline__ void store_out(float* p, float v) { *p = v; }

// async global->LDS, 16B/lane. LDS dest = wave-uniform base + lane*16.
__device__ __forceinline__ void gl2lds(const short* g, short* l) {
    __builtin_amdgcn_global_load_lds(
        (const __attribute__((address_space(1))) void*)g,
        (__attribute__((address_space(3))) void*)l, 16, 0, 0);
}

// --- W[k][n] fp32 -> Wt[z][n][k] bf16 ------------------------------------
__global__ __launch_bounds__(256) void prep_w(
    const float* __restrict__ W0, const float* __restrict__ W1,
    const float* __restrict__ W2, short* __restrict__ Wt)
{
    __shared__ float tile[64][65];
    const float* W = blockIdx.z == 0 ? W0 : (blockIdx.z == 1 ? W1 : W2);
    short* T = Wt + (size_t)blockIdx.z * 1048576;
    const int c0 = blockIdx.x * 64;
    const int r0 = blockIdx.y * 64;
    const int tx = threadIdx.x & 63;
    const int ty = threadIdx.x >> 6;
    #pragma unroll
    for (int p = 0; p < 16; ++p) {
        int r = ty + p * 4;
        tile[r][tx] = W[(size_t)(r0 + r) * 1024 + c0 + tx];
    }
    __syncthreads();
    #pragma unroll
    for (int p = 0; p < 16; ++p) {
        int r = ty + p * 4;
        T[(size_t)(c0 + r) * 1024 + r0 + tx] = f2bf(tile[tx][r]);
    }
}

// --- q,k,v fp32 -> xb bf16 -----------------------------------------------
__global__ __launch_bounds__(256) void cast_qkv(
    const float* __restrict__ q, const float* __restrict__ k,
    const float* __restrict__ v, short* __restrict__ xb)
{
    const float* src = blockIdx.z == 0 ? q : (blockIdx.z == 1 ? k : v);
    short* dst = xb + (size_t)blockIdx.z * 4194304;
    for (int i = blockIdx.x * 256 + threadIdx.x; i < 1048576; i += 256 * 1024) {
        float4 f = ((const float4*)src)[i];
        short4v o;
        o[0] = f2bf(f.x); o[1] = f2bf(f.y); o[2] = f2bf(f.z); o[3] = f2bf(f.w);
        ((short4v*)dst)[i] = o;
    }
}

// --- bf16 GEMM core: C = scale*(A @ Bt^T) [+ bias] ------------------------
// 128x128 tile, 4 waves (2x2 of 64x64), 2-slot LDS ring, BK=32.
// MODE 0: plain. MODE 1: z selects {A,Bt,C,bias}; z==2 writes Vt (transposed)
// instead of C. MODE 2: z is split-K index; C-dst = {C, P1, P2, P3}[z].
template <typename TOut, int MODE>
__global__ __launch_bounds__(256, 4) void gemm128(
    const short* __restrict__ A, const short* __restrict__ Bt,
    const float* __restrict__ b0, const float* __restrict__ b1,
    const float* __restrict__ b2,
    TOut* __restrict__ C, float* __restrict__ P1, float* __restrict__ P2,
    float* __restrict__ P3, short* __restrict__ Vt,
    int M, int N, int lda, int ldb, float scale,
    int nc, int nc_last, int kstep)
{
    // 2 slots x { A [128 rows][64B] = 8KB , B [128 rows][64B] = 8KB } = 32KB
    __shared__ short Lds[16384];

    const int t    = threadIdx.x;
    const int lane = t & 63;
    const int wv   = t >> 6;

    // ---- band-swizzled grid (XCD L2 locality): XCD x keeps m==x (mod 8). -
    const int nb  = gridDim.x;                    // n-tiles
    const int bid = blockIdx.y * nb + blockIdx.x;
    const int band   = bid / (8 * nb);
    const int within = bid - band * 8 * nb;
    const int m0 = (band * 8 + (within & 7)) * 128;
    const int n0 = (within >> 3) * 128;

    const float* bias = nullptr;
    int kbeg = 0;
    TOut* Cw = C;
    if constexpr (MODE == 1) {
        const int z = blockIdx.z;
        A  += (size_t)z * M * lda;
        Bt += (size_t)z * N * ldb;
        Cw  = C + (size_t)z * M * N;
        bias = z == 0 ? b0 : (z == 1 ? b1 : b2);
    }
    if constexpr (MODE == 2) {
        const int z = blockIdx.z;
        kbeg = z * kstep;
        if (z == (int)gridDim.z - 1) nc = nc_last;
        Cw = (TOut*)(z == 0 ? (float*)C : (z == 1 ? P1 : (z == 2 ? P2 : P3)));
    }
    (void)b0; (void)b1; (void)b2; (void)P1; (void)P2; (void)P3; (void)Vt;
    (void)nc_last; (void)kstep;

    // ---- staging map: per chunk each wave issues 4 gl2lds (1KB each):
    // A rows [wv*32,+16) and +16; B rows same on n0.
    // lane l -> row += l>>2, global 16B-col pre-swizzled (l&3)^((l>>3)&3).
    const int srow = lane >> 2;
    const int skof = ((lane & 3) ^ ((lane >> 3) & 3)) * 8;
    const short* pA0 = A  + (size_t)(m0 + wv * 32 + srow) * lda + kbeg + skof;
    const short* pA1 = pA0 + (size_t)16 * lda;
    const short* pB0 = Bt + (size_t)(n0 + wv * 32 + srow) * ldb + kbeg + skof;
    const short* pB1 = pB0 + (size_t)16 * ldb;
    short* sA0 = Lds + wv * 1024;           // wave-uniform LDS bases (shorts)
    short* sA1 = sA0 + 512;
    short* sB0 = Lds + 4096 + wv * 1024;
    short* sB1 = sB0 + 512;

    // ---- fragment read map (16x16x32: lane = lr + 16*lq) -----------------
    // physical 16B col = lq ^ ((lr>>1)&3) (lane-constant).
    const int wm = wv >> 1, wn = wv & 1;    // 2x2 wave grid
    const int lr = lane & 15, lq = lane >> 4;
    const int pcol = lq ^ ((lr >> 1) & 3);
    const short* rdA = Lds + (wm * 64 + lr) * 32 + pcol * 8;
    const short* rdB = Lds + 4096 + (wn * 64 + lr) * 32 + pcol * 8;

    f32x4 acc[4][4];
    #pragma unroll
    for (int i = 0; i < 4; ++i)
        #pragma unroll
        for (int j = 0; j < 4; ++j) { f32x4 z4 = {0.f,0.f,0.f,0.f}; acc[i][j] = z4; }

#define STAGE(c) {                                                        \
    const int s_ = (c) & 1;                                               \
    const size_t ko_ = (size_t)(c) * 32;                                  \
    gl2lds(pA0 + ko_, sA0 + s_ * 8192);                                   \
    gl2lds(pA1 + ko_, sA1 + s_ * 8192);                                   \
    gl2lds(pB0 + ko_, sB0 + s_ * 8192);                                   \
    gl2lds(pB1 + ko_, sB1 + s_ * 8192); }

#define COMPUTE(c) {                                                      \
    const short* rA_ = rdA + ((c) & 1) * 8192;                            \
    const short* rB_ = rdB + ((c) & 1) * 8192;                            \
    short8 af[4], bf_[4];                                                 \
    _Pragma("unroll") for (int i = 0; i < 4; ++i)                         \
        af[i] = *(const short8*)(rA_ + i * 512);                          \
    _Pragma("unroll") for (int j = 0; j < 4; ++j)                         \
        bf_[j] = *(const short8*)(rB_ + j * 512);                         \
    __builtin_amdgcn_s_setprio(1);                                        \
    _Pragma("unroll") for (int i = 0; i < 4; ++i)                         \
        _Pragma("unroll") for (int j = 0; j < 4; ++j)                     \
            acc[i][j] = MFMA16(af[i], bf_[j], acc[i][j], 0, 0, 0);        \
    __builtin_amdgcn_s_setprio(0); }

    // prologue: chunk 0 in flight.
    STAGE(0);

    // main loop: stage c+1, retire c (vmcnt(4) = leave c+1's 4 in flight),
    // barrier (all waves' c resident), compute c, barrier (slot (c+1)&1's
    // old reads drained before next iter's STAGE(c+2) overwrites it).
    for (int c = 0; c < nc - 1; ++c) {
        STAGE(c + 1);
        asm volatile("s_waitcnt vmcnt(4)" ::: "memory");
        __builtin_amdgcn_s_barrier();
        COMPUTE(c);
        __builtin_amdgcn_s_barrier();
    }
    // tail: no stage; drain and compute last chunk.
    asm volatile("s_waitcnt vmcnt(0)" ::: "memory");
    __builtin_amdgcn_s_barrier();
    COMPUTE(nc - 1);
#undef COMPUTE
#undef STAGE

    // ---- V-projection epilogue: write Vt[1024][4096] (transposed) --------
    if constexpr (MODE == 1) {
        if (blockIdx.z == 2) {
            // 2 passes of 64 cols through LDS [64][136] (8704 shorts <=16384)
            #pragma unroll
            for (int hh = 0; hh < 2; ++hh) {
                __syncthreads();
                if (wn == hh) {
                    #pragma unroll
                    for (int i = 0; i < 4; ++i) {
                        #pragma unroll
                        for (int j = 0; j < 4; ++j) {
                            const int colL = wn * 64 + j * 16 + lr;
                            const float bb = bias[n0 + colL];
                            #pragma unroll
                            for (int r = 0; r < 4; ++r) {
                                const int rowL = wm * 64 + i * 16 + lq * 4 + r;
                                Lds[(colL - 64 * hh) * 136 + rowL] =
                                    f2bf(acc[i][j][r] * scale + bb);
                            }
                        }
                    }
                }
                __syncthreads();
                const int c = t >> 2, part = t & 3;   // 64 rows x 4 parts
                short* dst = Vt + (size_t)(n0 + 64 * hh + c) * 4096
                                + m0 + part * 32;
                const short* src = &Lds[c * 136 + part * 32];
                #pragma unroll
                for (int s = 0; s < 4; ++s)
                    ((short8*)dst)[s] = ((const short8*)src)[s];
            }
            return;
        }
    }
    // ---- standard epilogue: C/D layout col=lane&15, row=(lane>>4)*4+reg --
    #pragma unroll
    for (int i = 0; i < 4; ++i) {
        const int crow = m0 + wm * 64 + i * 16 + lq * 4;
        #pragma unroll
        for (int j = 0; j < 4; ++j) {
            const int ccol = n0 + wn * 64 + j * 16 + lr;
            float bb = 0.f;
            if constexpr (MODE == 1) bb = bias[ccol];
            #pragma unroll
            for (int r = 0; r < 4; ++r) {
                float val = acc[i][j][r] * scale + bb;
                store_out(&Cw[(size_t)(crow + r) * N + ccol], val);
            }
        }
    }
}

// --- row softmax in place over bf16 S[4096][4096] -------------------------
__global__ __launch_bounds__(256) void softmax_bf16(short* __restrict__ S)
{
    const int row = blockIdx.x;
    short8* r8 = (short8*)(S + (size_t)row * 4096);
    const int t = threadIdx.x;

    float x[16];
    #pragma unroll
    for (int i = 0; i < 2; ++i) {
        short8 raw = r8[t + 256 * i];
        #pragma unroll
        for (int j = 0; j < 8; ++j) x[8 * i + j] = bf2f(raw[j]);
    }
    float m = -1e30f;
    #pragma unroll
    for (int i = 0; i < 16; ++i) m = fmaxf(m, x[i]);
    #pragma unroll
    for (int off = 32; off > 0; off >>= 1) m = fmaxf(m, __shfl_xor(m, off));

    __shared__ float redm[4], reds[4];
    const int wv = t >> 6;
    if ((t & 63) == 0) redm[wv] = m;
    __syncthreads();
    m = fmaxf(fmaxf(redm[0], redm[1]), fmaxf(redm[2], redm[3]));

    float s = 0.f;
    #pragma unroll
    for (int i = 0; i < 16; ++i) { x[i] = __expf(x[i] - m); s += x[i]; }
    #pragma unroll
    for (int off = 32; off > 0; off >>= 1) s += __shfl_xor(s, off);
    if ((t & 63) == 0) reds[wv] = s;
    __syncthreads();
    s = reds[0] + reds[1] + reds[2] + reds[3];
    const float inv = 1.f / s;

    #pragma unroll
    for (int i = 0; i < 2; ++i) {
        short8 o;
        #pragma unroll
        for (int j = 0; j < 8; ++j) o[j] = f2bf(x[8 * i + j] * inv);
        r8[t + 256 * i] = o;
    }
}

// --- out += p1 + p2 (+ p3) (split-K combine, in place) --------------------
__global__ __launch_bounds__(256) void combine(
    float* __restrict__ out, const float* __restrict__ a,
    const float* __restrict__ b, const float* __restrict__ c, int np)
{
    for (int i = blockIdx.x * 256 + threadIdx.x; i < 1048576; i += 256 * 1024) {
        float4 o = ((const float4*)out)[i];
        float4 x = ((const float4*)a)[i];
        float4 y = ((const float4*)b)[i];
        o.x += x.x + y.x; o.y += x.y + y.y;
        o.z += x.z + y.z; o.w += x.w + y.w;
        if (np == 3) {
            float4 w = ((const float4*)c)[i];
            o.x += w.x; o.y += w.y; o.z += w.z; o.w += w.w;
        }
        ((float4*)out)[i] = o;
    }
}

extern "C" void kernel_launch(void* const* d_in, const int* in_sizes, int n_in,
                              void* d_out, int out_size, void* d_ws, size_t ws_size,
                              hipStream_t stream)
{
    const float* q  = (const float*)d_in[0];
    const float* k  = (const float*)d_in[1];
    const float* v  = (const float*)d_in[2];
    const float* Wq = (const float*)d_in[3];
    const float* bq = (const float*)d_in[4];
    const float* Wk = (const float*)d_in[5];
    const float* bk = (const float*)d_in[6];
    const float* Wv = (const float*)d_in[7];
    const float* bv = (const float*)d_in[8];
    float* out = (float*)d_out;

    char* ws = (char*)d_ws;
    const size_t MB = 1ull << 20;
    short* Wt = (short*)(ws + 0);           // 3 x 1M shorts
    short* xb = (short*)(ws + 6 * MB);      // 3 x 4M shorts
    short* pr = (short*)(ws + 30 * MB);     // 2 x 4M shorts: Q, K
    short* S  = (short*)(ws + 46 * MB);     // 16M shorts
    short* Vt = (short*)(ws + 78 * MB);     // 4M shorts
    float* p1 = (float*)(ws + 0);           // dead Wt/xb region by PV time
    float* p2 = (float*)(ws + 16 * MB);
    float* p3 = (float*)(ws + 86 * MB);     // extra space, if available
    const int SK = (ws_size >= 102 * MB) ? 4 : 3;

    // 1) W^T + cast, q/k/v cast
    prep_w<<<dim3(16, 16, 3), 256, 0, stream>>>(Wq, Wk, Wv, Wt);
    cast_qkv<<<dim3(1024, 1, 3), 256, 0, stream>>>(q, k, v, xb);
    // 2) projections: Q,K -> pr; V -> Vt (transposed epilogue).
    //    grid 8n x 32m x 3 = 768 blocks (3/CU)
    gemm128<short, 1><<<dim3(8, 32, 3), 256, 0, stream>>>(
        xb, Wt, bq, bk, bv, pr, nullptr, nullptr, nullptr, Vt,
        4096, 1024, 1024, 1024, 1.f, 32, 32, 0);
    // 3) S = Q K^T / 32 ; grid 32n x 32m = 1024 blocks (4/CU)
    gemm128<short, 0><<<dim3(32, 32), 256, 0, stream>>>(
        pr, pr + 4 * 1024 * 1024, nullptr, nullptr, nullptr, S,
        nullptr, nullptr, nullptr, nullptr,
        4096, 4096, 1024, 1024, 0.03125f, 32, 32, 0);
    // 4) softmax rows in place (bf16)
    softmax_bf16<<<4096, 256, 0, stream>>>(S);
    // 5) partials = P @ V  (split-K; z=0 writes straight to out)
    if (SK == 4) {
        gemm128<float, 2><<<dim3(8, 32, 4), 256, 0, stream>>>(
            S, Vt, nullptr, nullptr, nullptr, out, p1, p2, p3, nullptr,
            4096, 1024, 4096, 4096, 1.f, 32, 32, 1024);
        combine<<<1024, 256, 0, stream>>>(out, p1, p2, p3, 3);
    } else {
        gemm128<float, 2><<<dim3(8, 32, 3), 256, 0, stream>>>(
            S, Vt, nullptr, nullptr, nullptr, out, p1, p2, nullptr, nullptr,
            4096, 1024, 4096, 4096, 1.f, 42, 44, 1344);
        combine<<<1024, 256, 0, stream>>>(out, p1, p2, nullptr, 2);
    }
}

// Round 9
// 262.790 us; speedup vs baseline: 1.0134x; 1.0008x over previous
//
#include <hip/hip_runtime.h>

// ---------------------------------------------------------------------------
// context = softmax((q@Wq+bq)(k@Wk+bk)^T / 32) @ (v@Wv+bv)
// S=4096, H=D=1024. fp32 in/out, bf16 MFMA internally.
//
// GEMM core (gemm128): 128x256 tile, 512 threads (8 waves, 2m x 4n of 64x64),
// BK=32 chunks through a 2-slot LDS ring (2 x 24KB = 48KB), 2 blocks/CU.
// MAIN LOOP IS BYTE-IDENTICAL TO ROUND 5 (best measured: QK 44.2us,
// FETCH 52MB, 0 bank conflicts). Changes are epilogue-only:
//  - bf16 outputs (S, Q/K proj): packed epilogue via LDS -> short8 stores.
//    (r5/r7 counters: scalar 2B stores inflate WRITE_SIZE 2x via RMW.)
//  - V-projection (z==2) writes Vt[1024][4096] directly via LDS transpose
//    (4 passes of 64 cols) -- kills transpose_v launch + 16MB round-trip.
//
// LDS bank swizzle (verified conflict-free r2/r5): logical 16B col k8 of
// row r lives at physical col k8 ^ ((r>>1)&3). Reads use lq ^ ((lr>>1)&3)
// (lane-constant); staging keeps the linear global_load_lds dest and
// pre-swizzles the per-lane GLOBAL k-offset: (l&3) ^ ((l>>3)&3).
//
// ws layout (MB):
//   [ 0, 6)  Wt  bf16 [3][1024][1024]      (W^T, per projection)
//   [ 6,30)  xb  bf16 [3][4096][1024]      (q,k,v cast)
//   [30,46)  pr  bf16 [2][4096][1024]      (Q,K projections)
//   [46,78)  S   bf16 [4096][4096]
//   [78,86)  Vt  bf16 [1024][4096]         (written by V-proj epilogue)
//   [ 0,16)  p1, [16,32) p2  fp32 partials (dead Wt/xb region at PV time)
//   [86,102) p3 fp32 partial               (only if ws_size >= 102MB -> SK=4)
// ---------------------------------------------------------------------------

typedef short short4v __attribute__((ext_vector_type(4)));
typedef short short8  __attribute__((ext_vector_type(8)));
typedef float f32x4   __attribute__((ext_vector_type(4)));

#define MFMA16 __builtin_amdgcn_mfma_f32_16x16x32_bf16

__device__ __forceinline__ short f2bf(float f) {
    union { float f; unsigned u; } x; x.f = f;
    unsigned r = (x.u + 0x7FFFu + ((x.u >> 16) & 1u)) >> 16;  // RNE
    return (short)r;
}
__device__ __forceinline__ float bf2f(short s) {
    union { unsigned u; float f; } x;
    x.u = ((unsigned)(unsigned short)s) << 16; return x.f;
}

// async global->LDS, 16B/lane. LDS dest = wave-uniform base + lane*16.
__device__ __forceinline__ void gl2lds(const short* g, short* l) {
    __builtin_amdgcn_global_load_lds(
        (const __attribute__((address_space(1))) void*)g,
        (__attribute__((address_space(3))) void*)l, 16, 0, 0);
}

// --- W[k][n] fp32 -> Wt[z][n][k] bf16 ------------------------------------
__global__ __launch_bounds__(256) void prep_w(
    const float* __restrict__ W0, const float* __restrict__ W1,
    const float* __restrict__ W2, short* __restrict__ Wt)
{
    __shared__ float tile[64][65];
    const float* W = blockIdx.z == 0 ? W0 : (blockIdx.z == 1 ? W1 : W2);
    short* T = Wt + (size_t)blockIdx.z * 1048576;
    const int c0 = blockIdx.x * 64;
    const int r0 = blockIdx.y * 64;
    const int tx = threadIdx.x & 63;
    const int ty = threadIdx.x >> 6;
    #pragma unroll
    for (int p = 0; p < 16; ++p) {
        int r = ty + p * 4;
        tile[r][tx] = W[(size_t)(r0 + r) * 1024 + c0 + tx];
    }
    __syncthreads();
    #pragma unroll
    for (int p = 0; p < 16; ++p) {
        int r = ty + p * 4;
        T[(size_t)(c0 + r) * 1024 + r0 + tx] = f2bf(tile[tx][r]);
    }
}

// --- q,k,v fp32 -> xb bf16 -----------------------------------------------
__global__ __launch_bounds__(256) void cast_qkv(
    const float* __restrict__ q, const float* __restrict__ k,
    const float* __restrict__ v, short* __restrict__ xb)
{
    const float* src = blockIdx.z == 0 ? q : (blockIdx.z == 1 ? k : v);
    short* dst = xb + (size_t)blockIdx.z * 4194304;
    for (int i = blockIdx.x * 256 + threadIdx.x; i < 1048576; i += 256 * 1024) {
        float4 f = ((const float4*)src)[i];
        short4v o;
        o[0] = f2bf(f.x); o[1] = f2bf(f.y); o[2] = f2bf(f.z); o[3] = f2bf(f.w);
        ((short4v*)dst)[i] = o;
    }
}

// --- bf16 GEMM core: C = scale*(A @ Bt^T) [+ bias] ------------------------
// 128x256 tile, 8 waves (2m x 4n, 64x64 each), 2-slot LDS ring, BK=32.
// MODE 0: plain. MODE 1: z selects {A,Bt,C,bias}; z==2 writes Vt (transposed).
// MODE 2: z is split-K index; C-dst = {C, P1, P2, P3}[z].
template <typename TOut, int MODE>
__global__ __launch_bounds__(512, 4) void gemm128(
    const short* __restrict__ A, const short* __restrict__ Bt,
    const float* __restrict__ b0, const float* __restrict__ b1,
    const float* __restrict__ b2,
    TOut* __restrict__ C, float* __restrict__ P1, float* __restrict__ P2,
    float* __restrict__ P3, short* __restrict__ Vt,
    int M, int N, int lda, int ldb, float scale,
    int nc, int nc_last, int kstep)
{
    // 2 slots x { A [128 rows][64B] = 8KB , B [256 rows][64B] = 16KB } = 48KB
    __shared__ short Lds[24576];

    const int t    = threadIdx.x;
    const int lane = t & 63;
    const int wv   = t >> 6;

    // ---- band-swizzled grid (XCD L2 locality): XCD x keeps m==x (mod 8). -
    const int nb  = gridDim.x;                    // n-tiles
    const int bid = blockIdx.y * nb + blockIdx.x;
    const int band   = bid / (8 * nb);
    const int within = bid - band * 8 * nb;
    const int m0 = (band * 8 + (within & 7)) * 128;
    const int n0 = (within >> 3) * 256;

    const float* bias = nullptr;
    int kbeg = 0;
    TOut* Cw = C;
    if constexpr (MODE == 1) {
        const int z = blockIdx.z;
        A  += (size_t)z * M * lda;
        Bt += (size_t)z * N * ldb;
        Cw  = C + (size_t)(z < 2 ? z : 0) * M * N;   // z==2 never writes C
        bias = z == 0 ? b0 : (z == 1 ? b1 : b2);
    }
    if constexpr (MODE == 2) {
        const int z = blockIdx.z;
        kbeg = z * kstep;
        if (z == (int)gridDim.z - 1) nc = nc_last;
        Cw = (TOut*)(z == 0 ? (float*)C : (z == 1 ? P1 : (z == 2 ? P2 : P3)));
    }
    (void)b0; (void)b1; (void)b2; (void)P1; (void)P2; (void)P3; (void)Vt;
    (void)nc_last; (void)kstep;

    // ---- staging map (identical to round 5): per chunk each wave issues
    // 3 gl2lds (1KB each): A rows [wv*16,+16); B rows [wv*16,+16) and +128.
    // lane l -> row += l>>2, global 16B-col pre-swizzled (l&3)^((l>>3)&3).
    const int srow = lane >> 2;
    const int skof = ((lane & 3) ^ ((lane >> 3) & 3)) * 8;
    const short* pA  = A  + (size_t)(m0 + wv * 16 + srow) * lda + kbeg + skof;
    const short* pB0 = Bt + (size_t)(n0 + wv * 16 + srow) * ldb + kbeg + skof;
    const short* pB1 = pB0 + (size_t)128 * ldb;
    short* sA  = Lds + wv * 512;            // wave-uniform LDS bases (shorts)
    short* sB0 = Lds + 4096 + wv * 512;
    short* sB1 = Lds + 8192 + wv * 512;

    // ---- fragment read map (16x16x32: lane = lr + 16*lq) -----------------
    // physical 16B col = lq ^ ((lr>>1)&3) (lane-constant).
    const int wm = wv >> 2, wn = wv & 3;    // 2m x 4n wave grid
    const int lr = lane & 15, lq = lane >> 4;
    const int pcol = lq ^ ((lr >> 1) & 3);
    const short* rdA = Lds + (wm * 64 + lr) * 32 + pcol * 8;
    const short* rdB = Lds + 4096 + (wn * 64 + lr) * 32 + pcol * 8;

    f32x4 acc[4][4];
    #pragma unroll
    for (int i = 0; i < 4; ++i)
        #pragma unroll
        for (int j = 0; j < 4; ++j) { f32x4 z4 = {0.f,0.f,0.f,0.f}; acc[i][j] = z4; }

#define STAGE(c) {                                                        \
    const int s_ = (c) & 1;                                               \
    const size_t ko_ = (size_t)(c) * 32;                                  \
    gl2lds(pA  + ko_, sA  + s_ * 12288);                                  \
    gl2lds(pB0 + ko_, sB0 + s_ * 12288);                                  \
    gl2lds(pB1 + ko_, sB1 + s_ * 12288); }

#define COMPUTE(c) {                                                      \
    const short* rA_ = rdA + ((c) & 1) * 12288;                           \
    const short* rB_ = rdB + ((c) & 1) * 12288;                           \
    short8 af[4], bf_[4];                                                 \
    _Pragma("unroll") for (int i = 0; i < 4; ++i)                         \
        af[i] = *(const short8*)(rA_ + i * 512);                          \
    _Pragma("unroll") for (int j = 0; j < 4; ++j)                         \
        bf_[j] = *(const short8*)(rB_ + j * 512);                         \
    __builtin_amdgcn_s_setprio(1);                                        \
    _Pragma("unroll") for (int i = 0; i < 4; ++i)                         \
        _Pragma("unroll") for (int j = 0; j < 4; ++j)                     \
            acc[i][j] = MFMA16(af[i], bf_[j], acc[i][j], 0, 0, 0);        \
    __builtin_amdgcn_s_setprio(0); }

    // prologue: chunk 0 in flight.
    STAGE(0);

    // main loop (round-5 verified): stage c+1, vmcnt(3), barrier, compute c,
    // barrier (slot (c+1)&1's old reads drained before STAGE(c+2)).
    for (int c = 0; c < nc - 1; ++c) {
        STAGE(c + 1);
        asm volatile("s_waitcnt vmcnt(3)" ::: "memory");
        __builtin_amdgcn_s_barrier();
        COMPUTE(c);
        __builtin_amdgcn_s_barrier();
    }
    // tail: no stage; drain and compute last chunk.
    asm volatile("s_waitcnt vmcnt(0)" ::: "memory");
    __builtin_amdgcn_s_barrier();
    COMPUTE(nc - 1);
#undef COMPUTE
#undef STAGE

    // ---- V-projection epilogue: write Vt[1024][4096] (transposed) --------
    // 4 passes over 64-col groups through LDS T[64 cols][136 rows-pad].
    if constexpr (MODE == 1) {
        if (blockIdx.z == 2) {
            #pragma unroll
            for (int hh = 0; hh < 4; ++hh) {
                __syncthreads();
                if (wn == hh) {
                    #pragma unroll
                    for (int i = 0; i < 4; ++i) {
                        #pragma unroll
                        for (int j = 0; j < 4; ++j) {
                            const int colL = j * 16 + lr;           // 0..63
                            const float bb = bias[n0 + hh * 64 + colL];
                            #pragma unroll
                            for (int r = 0; r < 4; ++r) {
                                const int rowL = wm * 64 + i * 16 + lq * 4 + r;
                                Lds[colL * 136 + rowL] =
                                    f2bf(acc[i][j][r] * scale + bb);
                            }
                        }
                    }
                }
                __syncthreads();
                const int c = t >> 3, part = t & 7;   // 64 rows x 8 parts
                short* dst = Vt + (size_t)(n0 + hh * 64 + c) * 4096
                                + m0 + part * 16;
                const short* src = &Lds[c * 136 + part * 16];
                *(short8*)dst       = *(const short8*)src;
                *(short8*)(dst + 8) = *(const short8*)(src + 8);
            }
            return;
        }
    }

    // ---- packed bf16 epilogue: LDS-pack -> short8 stores ------------------
    // (scalar 2B stores inflate WRITE_SIZE ~2x via partial-line RMW; pack
    //  the 128x256 tile in 2 passes of 64 rows through LDS [64][272].)
    if constexpr (sizeof(TOut) == 2) {
        #pragma unroll
        for (int p = 0; p < 2; ++p) {
            __syncthreads();
            if (wm == p) {
                #pragma unroll
                for (int i = 0; i < 4; ++i) {
                    #pragma unroll
                    for (int j = 0; j < 4; ++j) {
                        const int col = wn * 64 + j * 16 + lr;      // 0..255
                        float bb = 0.f;
                        if constexpr (MODE == 1) bb = bias[n0 + col];
                        #pragma unroll
                        for (int r = 0; r < 4; ++r) {
                            const int row = i * 16 + lq * 4 + r;    // 0..63
                            Lds[row * 272 + col] =
                                f2bf(acc[i][j][r] * scale + bb);
                        }
                    }
                }
            }
            __syncthreads();
            const int row = t >> 3, part = t & 7;   // 64 rows x 8 parts(32sh)
            short* dst = (short*)Cw + (size_t)(m0 + p * 64 + row) * N
                          + n0 + part * 32;
            const short* src = &Lds[row * 272 + part * 32];
            #pragma unroll
            for (int s = 0; s < 4; ++s)
                ((short8*)dst)[s] = ((const short8*)src)[s];
        }
        return;
    }

    // ---- direct fp32 epilogue (MODE 2): col=lane&15, row=(lane>>4)*4+reg -
    #pragma unroll
    for (int i = 0; i < 4; ++i) {
        const int crow = m0 + wm * 64 + i * 16 + lq * 4;
        #pragma unroll
        for (int j = 0; j < 4; ++j) {
            const int ccol = n0 + wn * 64 + j * 16 + lr;
            #pragma unroll
            for (int r = 0; r < 4; ++r)
                Cw[(size_t)(crow + r) * N + ccol] = acc[i][j][r] * scale;
        }
    }
}

// --- row softmax in place over bf16 S[4096][4096] -------------------------
__global__ __launch_bounds__(256) void softmax_bf16(short* __restrict__ S)
{
    const int row = blockIdx.x;
    short8* r8 = (short8*)(S + (size_t)row * 4096);
    const int t = threadIdx.x;

    float x[16];
    #pragma unroll
    for (int i = 0; i < 2; ++i) {
        short8 raw = r8[t + 256 * i];
        #pragma unroll
        for (int j = 0; j < 8; ++j) x[8 * i + j] = bf2f(raw[j]);
    }
    float m = -1e30f;
    #pragma unroll
    for (int i = 0; i < 16; ++i) m = fmaxf(m, x[i]);
    #pragma unroll
    for (int off = 32; off > 0; off >>= 1) m = fmaxf(m, __shfl_xor(m, off));

    __shared__ float redm[4], reds[4];
    const int wv = t >> 6;
    if ((t & 63) == 0) redm[wv] = m;
    __syncthreads();
    m = fmaxf(fmaxf(redm[0], redm[1]), fmaxf(redm[2], redm[3]));

    float s = 0.f;
    #pragma unroll
    for (int i = 0; i < 16; ++i) { x[i] = __expf(x[i] - m); s += x[i]; }
    #pragma unroll
    for (int off = 32; off > 0; off >>= 1) s += __shfl_xor(s, off);
    if ((t & 63) == 0) reds[wv] = s;
    __syncthreads();
    s = reds[0] + reds[1] + reds[2] + reds[3];
    const float inv = 1.f / s;

    #pragma unroll
    for (int i = 0; i < 2; ++i) {
        short8 o;
        #pragma unroll
        for (int j = 0; j < 8; ++j) o[j] = f2bf(x[8 * i + j] * inv);
        r8[t + 256 * i] = o;
    }
}

// --- out += p1 + p2 (+ p3) (split-K combine, in place) --------------------
__global__ __launch_bounds__(256) void combine(
    float* __restrict__ out, const float* __restrict__ a,
    const float* __restrict__ b, const float* __restrict__ c, int np)
{
    for (int i = blockIdx.x * 256 + threadIdx.x; i < 1048576; i += 256 * 1024) {
        float4 o = ((const float4*)out)[i];
        float4 x = ((const float4*)a)[i];
        float4 y = ((const float4*)b)[i];
        o.x += x.x + y.x; o.y += x.y + y.y;
        o.z += x.z + y.z; o.w += x.w + y.w;
        if (np == 3) {
            float4 w = ((const float4*)c)[i];
            o.x += w.x; o.y += w.y; o.z += w.z; o.w += w.w;
        }
        ((float4*)out)[i] = o;
    }
}

extern "C" void kernel_launch(void* const* d_in, const int* in_sizes, int n_in,
                              void* d_out, int out_size, void* d_ws, size_t ws_size,
                              hipStream_t stream)
{
    const float* q  = (const float*)d_in[0];
    const float* k  = (const float*)d_in[1];
    const float* v  = (const float*)d_in[2];
    const float* Wq = (const float*)d_in[3];
    const float* bq = (const float*)d_in[4];
    const float* Wk = (const float*)d_in[5];
    const float* bk = (const float*)d_in[6];
    const float* Wv = (const float*)d_in[7];
    const float* bv = (const float*)d_in[8];
    float* out = (float*)d_out;

    char* ws = (char*)d_ws;
    const size_t MB = 1ull << 20;
    short* Wt = (short*)(ws + 0);           // 3 x 1M shorts
    short* xb = (short*)(ws + 6 * MB);      // 3 x 4M shorts
    short* pr = (short*)(ws + 30 * MB);     // 2 x 4M shorts: Q, K
    short* S  = (short*)(ws + 46 * MB);     // 16M shorts
    short* Vt = (short*)(ws + 78 * MB);     // 4M shorts
    float* p1 = (float*)(ws + 0);           // dead Wt/xb region by PV time
    float* p2 = (float*)(ws + 16 * MB);
    float* p3 = (float*)(ws + 86 * MB);     // extra space, if available
    const int SK = (ws_size >= 102 * MB) ? 4 : 3;

    // 1) W^T + cast, q/k/v cast
    prep_w<<<dim3(16, 16, 3), 256, 0, stream>>>(Wq, Wk, Wv, Wt);
    cast_qkv<<<dim3(1024, 1, 3), 256, 0, stream>>>(q, k, v, xb);
    // 2) projections: Q,K -> pr; V -> Vt (transposed epilogue).
    //    grid 4n x 32m x 3 = 384 blocks (2/CU, single round)
    gemm128<short, 1><<<dim3(4, 32, 3), 512, 0, stream>>>(
        xb, Wt, bq, bk, bv, pr, nullptr, nullptr, nullptr, Vt,
        4096, 1024, 1024, 1024, 1.f, 32, 32, 0);
    // 3) S = Q K^T / 32 ; grid 16n x 32m = 512 blocks (2/CU exact)
    gemm128<short, 0><<<dim3(16, 32), 512, 0, stream>>>(
        pr, pr + 4 * 1024 * 1024, nullptr, nullptr, nullptr, S,
        nullptr, nullptr, nullptr, nullptr,
        4096, 4096, 1024, 1024, 0.03125f, 32, 32, 0);
    // 4) softmax rows in place (bf16)
    softmax_bf16<<<4096, 256, 0, stream>>>(S);
    // 5) partials = P @ V  (split-K; z=0 writes straight to out)
    if (SK == 4) {
        gemm128<float, 2><<<dim3(4, 32, 4), 512, 0, stream>>>(
            S, Vt, nullptr, nullptr, nullptr, out, p1, p2, p3, nullptr,
            4096, 1024, 4096, 4096, 1.f, 32, 32, 1024);
        combine<<<1024, 256, 0, stream>>>(out, p1, p2, p3, 3);
    } else {
        gemm128<float, 2><<<dim3(4, 32, 3), 512, 0, stream>>>(
            S, Vt, nullptr, nullptr, nullptr, out, p1, p2, nullptr, nullptr,
            4096, 1024, 4096, 4096, 1.f, 42, 44, 1344);
        combine<<<1024, 256, 0, stream>>>(out, p1, p2, nullptr, 2);
    }
}

// Round 10
// 261.143 us; speedup vs baseline: 1.0198x; 1.0063x over previous
//
#include <hip/hip_runtime.h>

// ---------------------------------------------------------------------------
// context = softmax((q@Wq+bq)(k@Wk+bk)^T / 32) @ (v@Wv+bv)
// S=4096, H=D=1024. fp32 in/out, bf16 MFMA internally.
//
// GEMM core (gemm128): 128x256 tile, 512 threads (8 waves, 2m x 4n of 64x64),
// BK=32 chunks, 2-slot LDS ring (48KB), 2 blocks/CU. Main loop = ROUND 5
// (best measured: QK 44.2us, 0 bank conflicts). r9's packed bf16 epilogue
// REVERTED (traffic halved but time +10%: kernel is latency-bound, not BW).
//
// Fusions:
//  - cast_qkv FUSED into projection GEMM: A-operand (q/k/v) read as fp32,
//    converted in-reg, ds_write_b128 into the same swizzled LDS layout the
//    gl2lds path uses (per-lane addr = base + lane*16, identical involution).
//    vmcnt: per iter issue {2x float4 A-loads, 2x gl2lds B}; waiting the A
//    regs = vmcnt(2) which also retires B(c) (same guarantee as r5 vmcnt(3));
//    lgkmcnt(0) before the barrier commits the ds_write.
//  - V-projection (z==2) writes Vt[1024][4096] via LDS transpose epilogue
//    (verified r9) -- no transpose_v kernel, no Vn round-trip.
//
// LDS bank swizzle (verified conflict-free r2/r5): logical 16B col k8 of
// row r lives at physical col k8 ^ ((r>>1)&3). Reads use lq ^ ((lr>>1)&3);
// staging pre-swizzles the per-lane GLOBAL k-offset (l&3)^((l>>3)&3).
//
// ws layout (MB):
//   [ 0, 6)  Wt  bf16 [3][1024][1024]      (W^T, per projection)
//   [30,46)  pr  bf16 [2][4096][1024]      (Q,K projections)
//   [46,78)  S   bf16 [4096][4096]
//   [78,86)  Vt  bf16 [1024][4096]         (written by V-proj epilogue)
//   [ 0,16)  p1, [16,32) p2  fp32 partials (dead Wt region by PV time)
//   [86,102) p3 fp32 partial               (only if ws_size >= 102MB -> SK=4)
// ---------------------------------------------------------------------------

typedef short short4v __attribute__((ext_vector_type(4)));
typedef short short8  __attribute__((ext_vector_type(8)));
typedef float f32x4   __attribute__((ext_vector_type(4)));

#define MFMA16 __builtin_amdgcn_mfma_f32_16x16x32_bf16

__device__ __forceinline__ short f2bf(float f) {
    union { float f; unsigned u; } x; x.f = f;
    unsigned r = (x.u + 0x7FFFu + ((x.u >> 16) & 1u)) >> 16;  // RNE
    return (short)r;
}
__device__ __forceinline__ float bf2f(short s) {
    union { unsigned u; float f; } x;
    x.u = ((unsigned)(unsigned short)s) << 16; return x.f;
}

// async global->LDS, 16B/lane. LDS dest = wave-uniform base + lane*16.
__device__ __forceinline__ void gl2lds(const short* g, short* l) {
    __builtin_amdgcn_global_load_lds(
        (const __attribute__((address_space(1))) void*)g,
        (__attribute__((address_space(3))) void*)l, 16, 0, 0);
}

// --- W[k][n] fp32 -> Wt[z][n][k] bf16 ------------------------------------
__global__ __launch_bounds__(256) void prep_w(
    const float* __restrict__ W0, const float* __restrict__ W1,
    const float* __restrict__ W2, short* __restrict__ Wt)
{
    __shared__ float tile[64][65];
    const float* W = blockIdx.z == 0 ? W0 : (blockIdx.z == 1 ? W1 : W2);
    short* T = Wt + (size_t)blockIdx.z * 1048576;
    const int c0 = blockIdx.x * 64;
    const int r0 = blockIdx.y * 64;
    const int tx = threadIdx.x & 63;
    const int ty = threadIdx.x >> 6;
    #pragma unroll
    for (int p = 0; p < 16; ++p) {
        int r = ty + p * 4;
        tile[r][tx] = W[(size_t)(r0 + r) * 1024 + c0 + tx];
    }
    __syncthreads();
    #pragma unroll
    for (int p = 0; p < 16; ++p) {
        int r = ty + p * 4;
        T[(size_t)(c0 + r) * 1024 + r0 + tx] = f2bf(tile[tx][r]);
    }
}

// --- bf16 GEMM core: C = scale*(A @ Bt^T) [+ bias] ------------------------
// TIn=float: A read fp32, converted, reg->LDS staged (fused cast).
// TIn=short: A staged via gl2lds (round-5 path).
// MODE 0: plain. MODE 1: z selects {A,Bt,C,bias}; z==2 writes Vt (transposed).
// MODE 2: z is split-K index; C-dst = {C, P1, P2, P3}[z].
template <typename TIn, typename TOut, int MODE>
__global__ __launch_bounds__(512, 4) void gemm128(
    const TIn* __restrict__ A0, const TIn* __restrict__ A1,
    const TIn* __restrict__ A2, const short* __restrict__ Bt,
    const float* __restrict__ b0, const float* __restrict__ b1,
    const float* __restrict__ b2,
    TOut* __restrict__ C, float* __restrict__ P1, float* __restrict__ P2,
    float* __restrict__ P3, short* __restrict__ Vt,
    int M, int N, int lda, int ldb, float scale,
    int nc, int nc_last, int kstep)
{
    // 2 slots x { A [128 rows][64B] = 8KB , B [256 rows][64B] = 16KB } = 48KB
    __shared__ short Lds[24576];

    const int t    = threadIdx.x;
    const int lane = t & 63;
    const int wv   = t >> 6;

    // ---- band-swizzled grid (XCD L2 locality): XCD x keeps m==x (mod 8). -
    const int nb  = gridDim.x;                    // n-tiles
    const int bid = blockIdx.y * nb + blockIdx.x;
    const int band   = bid / (8 * nb);
    const int within = bid - band * 8 * nb;
    const int m0 = (band * 8 + (within & 7)) * 128;
    const int n0 = (within >> 3) * 256;

    const TIn* A = A0;
    const float* bias = nullptr;
    int kbeg = 0;
    TOut* Cw = C;
    if constexpr (MODE == 1) {
        const int z = blockIdx.z;
        A = z == 0 ? A0 : (z == 1 ? A1 : A2);
        Bt += (size_t)z * N * ldb;
        Cw  = C + (size_t)(z < 2 ? z : 0) * M * N;   // z==2 never writes C
        bias = z == 0 ? b0 : (z == 1 ? b1 : b2);
    }
    if constexpr (MODE == 2) {
        const int z = blockIdx.z;
        kbeg = z * kstep;
        if (z == (int)gridDim.z - 1) nc = nc_last;
        Cw = (TOut*)(z == 0 ? (float*)C : (z == 1 ? P1 : (z == 2 ? P2 : P3)));
    }
    (void)A1; (void)A2; (void)b0; (void)b1; (void)b2;
    (void)P1; (void)P2; (void)P3; (void)Vt; (void)nc_last; (void)kstep;

    // ---- staging map: per chunk each wave covers A rows [wv*16,+16) and
    // B rows [wv*16,+16), +128. lane l -> row += l>>2, 8-elem col unit
    // pre-swizzled: (l&3)^((l>>3)&3). Same element indices for fp32/bf16.
    const int srow = lane >> 2;
    const int skof = ((lane & 3) ^ ((lane >> 3) & 3)) * 8;
    const TIn*  pA  = A  + (size_t)(m0 + wv * 16 + srow) * lda + kbeg + skof;
    const short* pB0 = Bt + (size_t)(n0 + wv * 16 + srow) * ldb + kbeg + skof;
    const short* pB1 = pB0 + (size_t)128 * ldb;
    short* sA  = Lds + wv * 512;            // wave-uniform LDS bases (shorts)
    short* sB0 = Lds + 4096 + wv * 512;
    short* sB1 = Lds + 8192 + wv * 512;
    short* sAw = Lds + wv * 512 + lane * 8; // per-lane A write base (fused)

    // ---- fragment read map (16x16x32: lane = lr + 16*lq) -----------------
    const int wm = wv >> 2, wn = wv & 3;    // 2m x 4n wave grid
    const int lr = lane & 15, lq = lane >> 4;
    const int pcol = lq ^ ((lr >> 1) & 3);
    const short* rdA = Lds + (wm * 64 + lr) * 32 + pcol * 8;
    const short* rdB = Lds + 4096 + (wn * 64 + lr) * 32 + pcol * 8;

    f32x4 acc[4][4];
    #pragma unroll
    for (int i = 0; i < 4; ++i)
        #pragma unroll
        for (int j = 0; j < 4; ++j) { f32x4 z4 = {0.f,0.f,0.f,0.f}; acc[i][j] = z4; }

#define STAGE_CHUNK(c) {                                                  \
    const int s_ = (c) & 1;                                               \
    const size_t ko_ = (size_t)(c) * 32;                                  \
    if constexpr (sizeof(TIn) == 4) {                                     \
        /* fused cast: fp32 A -> regs -> bf16 -> swizzled LDS */          \
        const float* asrc_ = (const float*)pA + ko_;                      \
        float4 fa0_ = *(const float4*)asrc_;                              \
        float4 fa1_ = *(const float4*)(asrc_ + 4);                        \
        gl2lds(pB0 + ko_, sB0 + s_ * 12288);                              \
        gl2lds(pB1 + ko_, sB1 + s_ * 12288);                              \
        short8 o_;                                                        \
        o_[0] = f2bf(fa0_.x); o_[1] = f2bf(fa0_.y);                       \
        o_[2] = f2bf(fa0_.z); o_[3] = f2bf(fa0_.w);                       \
        o_[4] = f2bf(fa1_.x); o_[5] = f2bf(fa1_.y);                       \
        o_[6] = f2bf(fa1_.z); o_[7] = f2bf(fa1_.w);                       \
        *(short8*)(sAw + s_ * 12288) = o_;                                \
    } else {                                                              \
        gl2lds((const short*)pA + ko_, sA + s_ * 12288);                  \
        gl2lds(pB0 + ko_, sB0 + s_ * 12288);                              \
        gl2lds(pB1 + ko_, sB1 + s_ * 12288);                              \
    } }

#define COMPUTE(c) {                                                      \
    const short* rA_ = rdA + ((c) & 1) * 12288;                           \
    const short* rB_ = rdB + ((c) & 1) * 12288;                           \
    short8 af[4], bf_[4];                                                 \
    _Pragma("unroll") for (int i = 0; i < 4; ++i)                         \
        af[i] = *(const short8*)(rA_ + i * 512);                          \
    _Pragma("unroll") for (int j = 0; j < 4; ++j)                         \
        bf_[j] = *(const short8*)(rB_ + j * 512);                         \
    __builtin_amdgcn_s_setprio(1);                                        \
    _Pragma("unroll") for (int i = 0; i < 4; ++i)                         \
        _Pragma("unroll") for (int j = 0; j < 4; ++j)                     \
            acc[i][j] = MFMA16(af[i], bf_[j], acc[i][j], 0, 0, 0);        \
    __builtin_amdgcn_s_setprio(0); }

    // prologue: chunk 0 staged (fused path: A(0) already ds_written).
    STAGE_CHUNK(0);

    // main loop: stage c+1; counted wait (A-reg use implies vmcnt(2) on the
    // fused path -- also retires B(c); plain path uses vmcnt(3)); lgkmcnt
    // commits the ds_write; barrier; compute c; barrier.
    for (int c = 0; c < nc - 1; ++c) {
        STAGE_CHUNK(c + 1);
        if constexpr (sizeof(TIn) == 4) {
            asm volatile("s_waitcnt vmcnt(2)" ::: "memory");
            asm volatile("s_waitcnt lgkmcnt(0)" ::: "memory");
        } else {
            asm volatile("s_waitcnt vmcnt(3)" ::: "memory");
        }
        __builtin_amdgcn_s_barrier();
        COMPUTE(c);
        __builtin_amdgcn_s_barrier();
    }
    // tail: drain and compute last chunk.
    asm volatile("s_waitcnt vmcnt(0)" ::: "memory");
    if constexpr (sizeof(TIn) == 4)
        asm volatile("s_waitcnt lgkmcnt(0)" ::: "memory");
    __builtin_amdgcn_s_barrier();
    COMPUTE(nc - 1);
#undef COMPUTE
#undef STAGE_CHUNK

    // ---- V-projection epilogue: write Vt[1024][4096] (transposed) --------
    if constexpr (MODE == 1) {
        if (blockIdx.z == 2) {
            #pragma unroll
            for (int hh = 0; hh < 4; ++hh) {
                __syncthreads();
                if (wn == hh) {
                    #pragma unroll
                    for (int i = 0; i < 4; ++i) {
                        #pragma unroll
                        for (int j = 0; j < 4; ++j) {
                            const int colL = j * 16 + lr;           // 0..63
                            const float bb = bias[n0 + hh * 64 + colL];
                            #pragma unroll
                            for (int r = 0; r < 4; ++r) {
                                const int rowL = wm * 64 + i * 16 + lq * 4 + r;
                                Lds[colL * 136 + rowL] =
                                    f2bf(acc[i][j][r] * scale + bb);
                            }
                        }
                    }
                }
                __syncthreads();
                const int c = t >> 3, part = t & 7;   // 64 rows x 8 parts
                short* dst = Vt + (size_t)(n0 + hh * 64 + c) * 4096
                                + m0 + part * 16;
                const short* src = &Lds[c * 136 + part * 16];
                *(short8*)dst       = *(const short8*)src;
                *(short8*)(dst + 8) = *(const short8*)(src + 8);
            }
            return;
        }
    }

    // ---- direct epilogue (round-5): col=lane&15, row=(lane>>4)*4+reg -----
    #pragma unroll
    for (int i = 0; i < 4; ++i) {
        const int crow = m0 + wm * 64 + i * 16 + lq * 4;
        #pragma unroll
        for (int j = 0; j < 4; ++j) {
            const int ccol = n0 + wn * 64 + j * 16 + lr;
            float bb = 0.f;
            if constexpr (MODE == 1) bb = bias[ccol];
            #pragma unroll
            for (int r = 0; r < 4; ++r) {
                float val = acc[i][j][r] * scale + bb;
                if constexpr (sizeof(TOut) == 2)
                    ((short*)Cw)[(size_t)(crow + r) * N + ccol] = f2bf(val);
                else
                    ((float*)Cw)[(size_t)(crow + r) * N + ccol] = val;
            }
        }
    }
}

// --- row softmax in place over bf16 S[4096][4096] -------------------------
__global__ __launch_bounds__(256) void softmax_bf16(short* __restrict__ S)
{
    const int row = blockIdx.x;
    short8* r8 = (short8*)(S + (size_t)row * 4096);
    const int t = threadIdx.x;

    float x[16];
    #pragma unroll
    for (int i = 0; i < 2; ++i) {
        short8 raw = r8[t + 256 * i];
        #pragma unroll
        for (int j = 0; j < 8; ++j) x[8 * i + j] = bf2f(raw[j]);
    }
    float m = -1e30f;
    #pragma unroll
    for (int i = 0; i < 16; ++i) m = fmaxf(m, x[i]);
    #pragma unroll
    for (int off = 32; off > 0; off >>= 1) m = fmaxf(m, __shfl_xor(m, off));

    __shared__ float redm[4], reds[4];
    const int wv = t >> 6;
    if ((t & 63) == 0) redm[wv] = m;
    __syncthreads();
    m = fmaxf(fmaxf(redm[0], redm[1]), fmaxf(redm[2], redm[3]));

    float s = 0.f;
    #pragma unroll
    for (int i = 0; i < 16; ++i) { x[i] = __expf(x[i] - m); s += x[i]; }
    #pragma unroll
    for (int off = 32; off > 0; off >>= 1) s += __shfl_xor(s, off);
    if ((t & 63) == 0) reds[wv] = s;
    __syncthreads();
    s = reds[0] + reds[1] + reds[2] + reds[3];
    const float inv = 1.f / s;

    #pragma unroll
    for (int i = 0; i < 2; ++i) {
        short8 o;
        #pragma unroll
        for (int j = 0; j < 8; ++j) o[j] = f2bf(x[8 * i + j] * inv);
        r8[t + 256 * i] = o;
    }
}

// --- out += p1 + p2 (+ p3) (split-K combine, in place) --------------------
__global__ __launch_bounds__(256) void combine(
    float* __restrict__ out, const float* __restrict__ a,
    const float* __restrict__ b, const float* __restrict__ c, int np)
{
    for (int i = blockIdx.x * 256 + threadIdx.x; i < 1048576; i += 256 * 1024) {
        float4 o = ((const float4*)out)[i];
        float4 x = ((const float4*)a)[i];
        float4 y = ((const float4*)b)[i];
        o.x += x.x + y.x; o.y += x.y + y.y;
        o.z += x.z + y.z; o.w += x.w + y.w;
        if (np == 3) {
            float4 w = ((const float4*)c)[i];
            o.x += w.x; o.y += w.y; o.z += w.z; o.w += w.w;
        }
        ((float4*)out)[i] = o;
    }
}

extern "C" void kernel_launch(void* const* d_in, const int* in_sizes, int n_in,
                              void* d_out, int out_size, void* d_ws, size_t ws_size,
                              hipStream_t stream)
{
    const float* q  = (const float*)d_in[0];
    const float* k  = (const float*)d_in[1];
    const float* v  = (const float*)d_in[2];
    const float* Wq = (const float*)d_in[3];
    const float* bq = (const float*)d_in[4];
    const float* Wk = (const float*)d_in[5];
    const float* bk = (const float*)d_in[6];
    const float* Wv = (const float*)d_in[7];
    const float* bv = (const float*)d_in[8];
    float* out = (float*)d_out;

    char* ws = (char*)d_ws;
    const size_t MB = 1ull << 20;
    short* Wt = (short*)(ws + 0);           // 3 x 1M shorts
    short* pr = (short*)(ws + 30 * MB);     // 2 x 4M shorts: Q, K
    short* S  = (short*)(ws + 46 * MB);     // 16M shorts
    short* Vt = (short*)(ws + 78 * MB);     // 4M shorts
    float* p1 = (float*)(ws + 0);           // dead Wt region by PV time
    float* p2 = (float*)(ws + 16 * MB);
    float* p3 = (float*)(ws + 86 * MB);     // extra space, if available
    const int SK = (ws_size >= 102 * MB) ? 4 : 3;

    // 1) W^T + cast
    prep_w<<<dim3(16, 16, 3), 256, 0, stream>>>(Wq, Wk, Wv, Wt);
    // 2) projections (fused fp32 cast): Q,K -> pr; V -> Vt (transposed).
    gemm128<float, short, 1><<<dim3(4, 32, 3), 512, 0, stream>>>(
        q, k, v, Wt, bq, bk, bv, pr, nullptr, nullptr, nullptr, Vt,
        4096, 1024, 1024, 1024, 1.f, 32, 32, 0);
    // 3) S = Q K^T / 32 ; grid 16n x 32m = 512 blocks (2/CU exact)
    gemm128<short, short, 0><<<dim3(16, 32), 512, 0, stream>>>(
        pr, nullptr, nullptr, pr + 4 * 1024 * 1024,
        nullptr, nullptr, nullptr, S, nullptr, nullptr, nullptr, nullptr,
        4096, 4096, 1024, 1024, 0.03125f, 32, 32, 0);
    // 4) softmax rows in place (bf16)
    softmax_bf16<<<4096, 256, 0, stream>>>(S);
    // 5) partials = P @ V  (split-K; z=0 writes straight to out)
    if (SK == 4) {
        gemm128<short, float, 2><<<dim3(4, 32, 4), 512, 0, stream>>>(
            S, nullptr, nullptr, Vt, nullptr, nullptr, nullptr,
            out, p1, p2, p3, nullptr,
            4096, 1024, 4096, 4096, 1.f, 32, 32, 1024);
        combine<<<1024, 256, 0, stream>>>(out, p1, p2, p3, 3);
    } else {
        gemm128<short, float, 2><<<dim3(4, 32, 3), 512, 0, stream>>>(
            S, nullptr, nullptr, Vt, nullptr, nullptr, nullptr,
            out, p1, p2, nullptr, nullptr,
            4096, 1024, 4096, 4096, 1.f, 42, 44, 1344);
        combine<<<1024, 256, 0, stream>>>(out, p1, p2, nullptr, 2);
    }
}

// Round 11
// 260.571 us; speedup vs baseline: 1.0220x; 1.0022x over previous
//
#include <hip/hip_runtime.h>

// ---------------------------------------------------------------------------
// context = softmax((q@Wq+bq)(k@Wk+bk)^T / 32) @ (v@Wv+bv)
// S=4096, H=D=1024. fp32 in/out, bf16 MFMA internally.
//
// GEMM core (gemm128): 128x256 tile, 512 threads (8 waves, 2m x 4n of 64x64),
// BK=32 chunks, 2-slot LDS ring (48KB), 2 blocks/CU. bf16 path = ROUND 5
// main loop (best measured: QK 44.2us, 0 bank conflicts).
//
// Fused cast (fp32 A) -- ROUND 11 FIX of r10's +45us regression: A-register
// loads are now issued ONE CHUNK AHEAD (T14 issue-early/write-late).
// r10 issued + converted + waited the same chunk's loads back-to-back ->
// full HBM latency exposed per chunk (proj 70us, all pipes idle).
// Now: iter c issues A(c+2)->regs (X/Y parity, 2-unrolled loop for static
// names), gl2lds B(c+1), converts/ds_writes A(c+1) (loaded a full iter ago),
// vmcnt(4) retires {A(c+1) regs, B(c)}, leaves {A(c+2), B(c+1)} in flight.
// Tail: vmcnt(2) at c=nc-2, vmcnt(0) before last compute. nc is even.
//
// V-projection (z==2) writes Vt[1024][4096] via LDS transpose epilogue
// (verified r9/r10) -- no transpose_v kernel, no Vn round-trip.
//
// LDS bank swizzle (verified conflict-free r2/r5): logical 16B col k8 of
// row r lives at physical col k8 ^ ((r>>1)&3). Reads use lq ^ ((lr>>1)&3);
// staging pre-swizzles the per-lane GLOBAL k-offset (l&3)^((l>>3)&3).
// Fused path ds_writes at base + lane*16B = same linear layout as gl2lds.
//
// ws layout (MB):
//   [ 0, 6)  Wt  bf16 [3][1024][1024]      (W^T, per projection)
//   [30,46)  pr  bf16 [2][4096][1024]      (Q,K projections)
//   [46,78)  S   bf16 [4096][4096]
//   [78,86)  Vt  bf16 [1024][4096]         (written by V-proj epilogue)
//   [ 0,16)  p1, [16,32) p2  fp32 partials (dead Wt region by PV time)
//   [86,102) p3 fp32 partial               (only if ws_size >= 102MB -> SK=4)
// ---------------------------------------------------------------------------

typedef short short4v __attribute__((ext_vector_type(4)));
typedef short short8  __attribute__((ext_vector_type(8)));
typedef float f32x4   __attribute__((ext_vector_type(4)));

#define MFMA16 __builtin_amdgcn_mfma_f32_16x16x32_bf16

__device__ __forceinline__ short f2bf(float f) {
    union { float f; unsigned u; } x; x.f = f;
    unsigned r = (x.u + 0x7FFFu + ((x.u >> 16) & 1u)) >> 16;  // RNE
    return (short)r;
}
__device__ __forceinline__ float bf2f(short s) {
    union { unsigned u; float f; } x;
    x.u = ((unsigned)(unsigned short)s) << 16; return x.f;
}

// async global->LDS, 16B/lane. LDS dest = wave-uniform base + lane*16.
__device__ __forceinline__ void gl2lds(const short* g, short* l) {
    __builtin_amdgcn_global_load_lds(
        (const __attribute__((address_space(1))) void*)g,
        (__attribute__((address_space(3))) void*)l, 16, 0, 0);
}

// --- W[k][n] fp32 -> Wt[z][n][k] bf16 ------------------------------------
__global__ __launch_bounds__(256) void prep_w(
    const float* __restrict__ W0, const float* __restrict__ W1,
    const float* __restrict__ W2, short* __restrict__ Wt)
{
    __shared__ float tile[64][65];
    const float* W = blockIdx.z == 0 ? W0 : (blockIdx.z == 1 ? W1 : W2);
    short* T = Wt + (size_t)blockIdx.z * 1048576;
    const int c0 = blockIdx.x * 64;
    const int r0 = blockIdx.y * 64;
    const int tx = threadIdx.x & 63;
    const int ty = threadIdx.x >> 6;
    #pragma unroll
    for (int p = 0; p < 16; ++p) {
        int r = ty + p * 4;
        tile[r][tx] = W[(size_t)(r0 + r) * 1024 + c0 + tx];
    }
    __syncthreads();
    #pragma unroll
    for (int p = 0; p < 16; ++p) {
        int r = ty + p * 4;
        T[(size_t)(c0 + r) * 1024 + r0 + tx] = f2bf(tile[tx][r]);
    }
}

// --- bf16 GEMM core: C = scale*(A @ Bt^T) [+ bias] ------------------------
// TIn=float: A read fp32, pipelined reg-staging (fused cast, T14).
// TIn=short: A staged via gl2lds (round-5 path).
// MODE 0: plain. MODE 1: z selects {A,Bt,C,bias}; z==2 writes Vt (transposed).
// MODE 2: z is split-K index; C-dst = {C, P1, P2, P3}[z].
template <typename TIn, typename TOut, int MODE>
__global__ __launch_bounds__(512, 4) void gemm128(
    const TIn* __restrict__ A0, const TIn* __restrict__ A1,
    const TIn* __restrict__ A2, const short* __restrict__ Bt,
    const float* __restrict__ b0, const float* __restrict__ b1,
    const float* __restrict__ b2,
    TOut* __restrict__ C, float* __restrict__ P1, float* __restrict__ P2,
    float* __restrict__ P3, short* __restrict__ Vt,
    int M, int N, int lda, int ldb, float scale,
    int nc, int nc_last, int kstep)
{
    // 2 slots x { A [128 rows][64B] = 8KB , B [256 rows][64B] = 16KB } = 48KB
    __shared__ short Lds[24576];

    const int t    = threadIdx.x;
    const int lane = t & 63;
    const int wv   = t >> 6;

    // ---- band-swizzled grid (XCD L2 locality): XCD x keeps m==x (mod 8). -
    const int nb  = gridDim.x;                    // n-tiles
    const int bid = blockIdx.y * nb + blockIdx.x;
    const int band   = bid / (8 * nb);
    const int within = bid - band * 8 * nb;
    const int m0 = (band * 8 + (within & 7)) * 128;
    const int n0 = (within >> 3) * 256;

    const TIn* A = A0;
    const float* bias = nullptr;
    int kbeg = 0;
    TOut* Cw = C;
    if constexpr (MODE == 1) {
        const int z = blockIdx.z;
        A = z == 0 ? A0 : (z == 1 ? A1 : A2);
        Bt += (size_t)z * N * ldb;
        Cw  = C + (size_t)(z < 2 ? z : 0) * M * N;   // z==2 never writes C
        bias = z == 0 ? b0 : (z == 1 ? b1 : b2);
    }
    if constexpr (MODE == 2) {
        const int z = blockIdx.z;
        kbeg = z * kstep;
        if (z == (int)gridDim.z - 1) nc = nc_last;
        Cw = (TOut*)(z == 0 ? (float*)C : (z == 1 ? P1 : (z == 2 ? P2 : P3)));
    }
    (void)A1; (void)A2; (void)b0; (void)b1; (void)b2;
    (void)P1; (void)P2; (void)P3; (void)Vt; (void)nc_last; (void)kstep;

    // ---- staging map: per chunk each wave covers A rows [wv*16,+16) and
    // B rows [wv*16,+16), +128. lane l -> row += l>>2, 8-elem col unit
    // pre-swizzled: (l&3)^((l>>3)&3). Same element indices for fp32/bf16.
    const int srow = lane >> 2;
    const int skof = ((lane & 3) ^ ((lane >> 3) & 3)) * 8;
    const TIn*  pA  = A  + (size_t)(m0 + wv * 16 + srow) * lda + kbeg + skof;
    const short* pB0 = Bt + (size_t)(n0 + wv * 16 + srow) * ldb + kbeg + skof;
    const short* pB1 = pB0 + (size_t)128 * ldb;
    short* sA  = Lds + wv * 512;            // wave-uniform LDS bases (shorts)
    short* sB0 = Lds + 4096 + wv * 512;
    short* sB1 = Lds + 8192 + wv * 512;
    short* sAw = Lds + wv * 512 + lane * 8; // per-lane A write base (fused)

    // ---- fragment read map (16x16x32: lane = lr + 16*lq) -----------------
    const int wm = wv >> 2, wn = wv & 3;    // 2m x 4n wave grid
    const int lr = lane & 15, lq = lane >> 4;
    const int pcol = lq ^ ((lr >> 1) & 3);
    const short* rdA = Lds + (wm * 64 + lr) * 32 + pcol * 8;
    const short* rdB = Lds + 4096 + (wn * 64 + lr) * 32 + pcol * 8;

    f32x4 acc[4][4];
    #pragma unroll
    for (int i = 0; i < 4; ++i)
        #pragma unroll
        for (int j = 0; j < 4; ++j) { f32x4 z4 = {0.f,0.f,0.f,0.f}; acc[i][j] = z4; }

#define COMPUTE(c) {                                                      \
    const short* rA_ = rdA + ((c) & 1) * 12288;                           \
    const short* rB_ = rdB + ((c) & 1) * 12288;                           \
    short8 af[4], bf_[4];                                                 \
    _Pragma("unroll") for (int i = 0; i < 4; ++i)                         \
        af[i] = *(const short8*)(rA_ + i * 512);                          \
    _Pragma("unroll") for (int j = 0; j < 4; ++j)                         \
        bf_[j] = *(const short8*)(rB_ + j * 512);                         \
    __builtin_amdgcn_s_setprio(1);                                        \
    _Pragma("unroll") for (int i = 0; i < 4; ++i)                         \
        _Pragma("unroll") for (int j = 0; j < 4; ++j)                     \
            acc[i][j] = MFMA16(af[i], bf_[j], acc[i][j], 0, 0, 0);        \
    __builtin_amdgcn_s_setprio(0); }

#define CVT_WRITE(W0r, W1r, slot) {                                       \
    short8 o_;                                                            \
    o_[0] = f2bf(W0r.x); o_[1] = f2bf(W0r.y);                             \
    o_[2] = f2bf(W0r.z); o_[3] = f2bf(W0r.w);                             \
    o_[4] = f2bf(W1r.x); o_[5] = f2bf(W1r.y);                             \
    o_[6] = f2bf(W1r.z); o_[7] = f2bf(W1r.w);                             \
    *(short8*)(sAw + (slot) * 12288) = o_; }

    if constexpr (sizeof(TIn) == 4) {
        // ================= fused-cast pipelined path (T14) ================
        const float* aG = (const float*)pA;
        float4 X0, X1, Y0, Y1;

        // prologue: A(0)->p (written now), A(1)->X, gl2lds B(0).
        {
            float4 p0 = *(const float4*)(aG + 0);
            float4 p1 = *(const float4*)(aG + 4);
            X0 = *(const float4*)(aG + 32);
            X1 = *(const float4*)(aG + 36);
            gl2lds(pB0, sB0);
            gl2lds(pB1, sB1);
            CVT_WRITE(p0, p1, 0);   // compiler inserts the wait for p0/p1
        }

        // iter c: issue A(c+2)->Lreg, gl2lds B(c+1), write A(c+1) from Wreg
        // (loaded one full iteration earlier), vmcnt(4) -> retires
        // {A(c+1) regs, B(c)}, leaves {A(c+2), B(c+1)} in flight.
#define FITER(c, Wr0, Wr1, Lr0, Lr1) {                                    \
    const int s_ = ((c) + 1) & 1;                                         \
    const size_t kn_ = (size_t)((c) + 2) * 32;                            \
    Lr0 = *(const float4*)(aG + kn_);                                     \
    Lr1 = *(const float4*)(aG + kn_ + 4);                                 \
    gl2lds(pB0 + ((c) + 1) * 32, sB0 + s_ * 12288);                       \
    gl2lds(pB1 + ((c) + 1) * 32, sB1 + s_ * 12288);                       \
    CVT_WRITE(Wr0, Wr1, s_);                                              \
    asm volatile("s_waitcnt vmcnt(4)" ::: "memory");                      \
    asm volatile("s_waitcnt lgkmcnt(0)" ::: "memory");                    \
    __builtin_amdgcn_s_barrier();                                         \
    COMPUTE(c);                                                           \
    __builtin_amdgcn_s_barrier(); }

        // main: pairs (c even). nc is even; covers c = 0 .. nc-3.
        for (int c = 0; c < nc - 2; c += 2) {
            FITER(c,     X0, X1, Y0, Y1);
            FITER(c + 1, Y0, Y1, X0, X1);
        }
        // c = nc-2: no A issue; write A(nc-1) from X (nc-1 odd -> X).
        {
            const int s_ = (nc - 1) & 1;
            gl2lds(pB0 + (nc - 1) * 32, sB0 + s_ * 12288);
            gl2lds(pB1 + (nc - 1) * 32, sB1 + s_ * 12288);
            CVT_WRITE(X0, X1, s_);
            asm volatile("s_waitcnt vmcnt(2)" ::: "memory");
            asm volatile("s_waitcnt lgkmcnt(0)" ::: "memory");
            __builtin_amdgcn_s_barrier();
            COMPUTE(nc - 2);
            __builtin_amdgcn_s_barrier();
        }
        // tail: retire B(nc-1), compute last chunk.
        asm volatile("s_waitcnt vmcnt(0)" ::: "memory");
        __builtin_amdgcn_s_barrier();
        COMPUTE(nc - 1);
#undef FITER
    } else {
        // ================= round-5 gl2lds path (verified best) ============
#define STAGE(c) {                                                        \
    const int s_ = (c) & 1;                                               \
    const size_t ko_ = (size_t)(c) * 32;                                  \
    gl2lds((const short*)pA + ko_, sA + s_ * 12288);                      \
    gl2lds(pB0 + ko_, sB0 + s_ * 12288);                                  \
    gl2lds(pB1 + ko_, sB1 + s_ * 12288);  }
        STAGE(0);
        for (int c = 0; c < nc - 1; ++c) {
            STAGE(c + 1);
            asm volatile("s_waitcnt vmcnt(3)" ::: "memory");
            __builtin_amdgcn_s_barrier();
            COMPUTE(c);
            __builtin_amdgcn_s_barrier();
        }
        asm volatile("s_waitcnt vmcnt(0)" ::: "memory");
        __builtin_amdgcn_s_barrier();
        COMPUTE(nc - 1);
#undef STAGE
    }
#undef CVT_WRITE
#undef COMPUTE

    // ---- V-projection epilogue: write Vt[1024][4096] (transposed) --------
    if constexpr (MODE == 1) {
        if (blockIdx.z == 2) {
            #pragma unroll
            for (int hh = 0; hh < 4; ++hh) {
                __syncthreads();
                if (wn == hh) {
                    #pragma unroll
                    for (int i = 0; i < 4; ++i) {
                        #pragma unroll
                        for (int j = 0; j < 4; ++j) {
                            const int colL = j * 16 + lr;           // 0..63
                            const float bb = bias[n0 + hh * 64 + colL];
                            #pragma unroll
                            for (int r = 0; r < 4; ++r) {
                                const int rowL = wm * 64 + i * 16 + lq * 4 + r;
                                Lds[colL * 136 + rowL] =
                                    f2bf(acc[i][j][r] * scale + bb);
                            }
                        }
                    }
                }
                __syncthreads();
                const int c = t >> 3, part = t & 7;   // 64 rows x 8 parts
                short* dst = Vt + (size_t)(n0 + hh * 64 + c) * 4096
                                + m0 + part * 16;
                const short* src = &Lds[c * 136 + part * 16];
                *(short8*)dst       = *(const short8*)src;
                *(short8*)(dst + 8) = *(const short8*)(src + 8);
            }
            return;
        }
    }

    // ---- direct epilogue (round-5): col=lane&15, row=(lane>>4)*4+reg -----
    #pragma unroll
    for (int i = 0; i < 4; ++i) {
        const int crow = m0 + wm * 64 + i * 16 + lq * 4;
        #pragma unroll
        for (int j = 0; j < 4; ++j) {
            const int ccol = n0 + wn * 64 + j * 16 + lr;
            float bb = 0.f;
            if constexpr (MODE == 1) bb = bias[ccol];
            #pragma unroll
            for (int r = 0; r < 4; ++r) {
                float val = acc[i][j][r] * scale + bb;
                if constexpr (sizeof(TOut) == 2)
                    ((short*)Cw)[(size_t)(crow + r) * N + ccol] = f2bf(val);
                else
                    ((float*)Cw)[(size_t)(crow + r) * N + ccol] = val;
            }
        }
    }
}

// --- row softmax in place over bf16 S[4096][4096] -------------------------
__global__ __launch_bounds__(256) void softmax_bf16(short* __restrict__ S)
{
    const int row = blockIdx.x;
    short8* r8 = (short8*)(S + (size_t)row * 4096);
    const int t = threadIdx.x;

    float x[16];
    #pragma unroll
    for (int i = 0; i < 2; ++i) {
        short8 raw = r8[t + 256 * i];
        #pragma unroll
        for (int j = 0; j < 8; ++j) x[8 * i + j] = bf2f(raw[j]);
    }
    float m = -1e30f;
    #pragma unroll
    for (int i = 0; i < 16; ++i) m = fmaxf(m, x[i]);
    #pragma unroll
    for (int off = 32; off > 0; off >>= 1) m = fmaxf(m, __shfl_xor(m, off));

    __shared__ float redm[4], reds[4];
    const int wv = t >> 6;
    if ((t & 63) == 0) redm[wv] = m;
    __syncthreads();
    m = fmaxf(fmaxf(redm[0], redm[1]), fmaxf(redm[2], redm[3]));

    float s = 0.f;
    #pragma unroll
    for (int i = 0; i < 16; ++i) { x[i] = __expf(x[i] - m); s += x[i]; }
    #pragma unroll
    for (int off = 32; off > 0; off >>= 1) s += __shfl_xor(s, off);
    if ((t & 63) == 0) reds[wv] = s;
    __syncthreads();
    s = reds[0] + reds[1] + reds[2] + reds[3];
    const float inv = 1.f / s;

    #pragma unroll
    for (int i = 0; i < 2; ++i) {
        short8 o;
        #pragma unroll
        for (int j = 0; j < 8; ++j) o[j] = f2bf(x[8 * i + j] * inv);
        r8[t + 256 * i] = o;
    }
}

// --- out += p1 + p2 (+ p3) (split-K combine, in place) --------------------
__global__ __launch_bounds__(256) void combine(
    float* __restrict__ out, const float* __restrict__ a,
    const float* __restrict__ b, const float* __restrict__ c, int np)
{
    for (int i = blockIdx.x * 256 + threadIdx.x; i < 1048576; i += 256 * 1024) {
        float4 o = ((const float4*)out)[i];
        float4 x = ((const float4*)a)[i];
        float4 y = ((const float4*)b)[i];
        o.x += x.x + y.x; o.y += x.y + y.y;
        o.z += x.z + y.z; o.w += x.w + y.w;
        if (np == 3) {
            float4 w = ((const float4*)c)[i];
            o.x += w.x; o.y += w.y; o.z += w.z; o.w += w.w;
        }
        ((float4*)out)[i] = o;
    }
}

extern "C" void kernel_launch(void* const* d_in, const int* in_sizes, int n_in,
                              void* d_out, int out_size, void* d_ws, size_t ws_size,
                              hipStream_t stream)
{
    const float* q  = (const float*)d_in[0];
    const float* k  = (const float*)d_in[1];
    const float* v  = (const float*)d_in[2];
    const float* Wq = (const float*)d_in[3];
    const float* bq = (const float*)d_in[4];
    const float* Wk = (const float*)d_in[5];
    const float* bk = (const float*)d_in[6];
    const float* Wv = (const float*)d_in[7];
    const float* bv = (const float*)d_in[8];
    float* out = (float*)d_out;

    char* ws = (char*)d_ws;
    const size_t MB = 1ull << 20;
    short* Wt = (short*)(ws + 0);           // 3 x 1M shorts
    short* pr = (short*)(ws + 30 * MB);     // 2 x 4M shorts: Q, K
    short* S  = (short*)(ws + 46 * MB);     // 16M shorts
    short* Vt = (short*)(ws + 78 * MB);     // 4M shorts
    float* p1 = (float*)(ws + 0);           // dead Wt region by PV time
    float* p2 = (float*)(ws + 16 * MB);
    float* p3 = (float*)(ws + 86 * MB);     // extra space, if available
    const int SK = (ws_size >= 102 * MB) ? 4 : 3;

    // 1) W^T + cast
    prep_w<<<dim3(16, 16, 3), 256, 0, stream>>>(Wq, Wk, Wv, Wt);
    // 2) projections (fused fp32 cast, pipelined): Q,K -> pr; V -> Vt.
    gemm128<float, short, 1><<<dim3(4, 32, 3), 512, 0, stream>>>(
        q, k, v, Wt, bq, bk, bv, pr, nullptr, nullptr, nullptr, Vt,
        4096, 1024, 1024, 1024, 1.f, 32, 32, 0);
    // 3) S = Q K^T / 32 ; grid 16n x 32m = 512 blocks (2/CU exact)
    gemm128<short, short, 0><<<dim3(16, 32), 512, 0, stream>>>(
        pr, nullptr, nullptr, pr + 4 * 1024 * 1024,
        nullptr, nullptr, nullptr, S, nullptr, nullptr, nullptr, nullptr,
        4096, 4096, 1024, 1024, 0.03125f, 32, 32, 0);
    // 4) softmax rows in place (bf16)
    softmax_bf16<<<4096, 256, 0, stream>>>(S);
    // 5) partials = P @ V  (split-K; z=0 writes straight to out)
    if (SK == 4) {
        gemm128<short, float, 2><<<dim3(4, 32, 4), 512, 0, stream>>>(
            S, nullptr, nullptr, Vt, nullptr, nullptr, nullptr,
            out, p1, p2, p3, nullptr,
            4096, 1024, 4096, 4096, 1.f, 32, 32, 1024);
        combine<<<1024, 256, 0, stream>>>(out, p1, p2, p3, 3);
    } else {
        gemm128<short, float, 2><<<dim3(4, 32, 3), 512, 0, stream>>>(
            S, nullptr, nullptr, Vt, nullptr, nullptr, nullptr,
            out, p1, p2, nullptr, nullptr,
            4096, 1024, 4096, 4096, 1.f, 42, 44, 1344);
        combine<<<1024, 256, 0, stream>>>(out, p1, p2, nullptr, 2);
    }
}